// Round 9
// baseline (415.692 us; speedup 1.0000x reference)
//
#include <hip/hip_runtime.h>
#include <hip/hip_bf16.h>
#include <math.h>

// B=4, S=2048, D=256, H=4, HD=64; keep top-10% per score row.
// thr = v206 + 0.3*(v205 - v206)  (v_k = k-th largest), exact via bit-bisection.
//
// This round:
//  - attn: un-hoist Q fragments (reload per chunk) to drop score-phase register
//    peak below the 128 cap -> su[64] stays in arch VGPRs, killing ~1-2K
//    v_accvgpr bounce instructions/wave in selection (the VALU-issue excess).
//  - xpart: 512 blocks (16-row partials) instead of 64 blocks x 128-deep chains
//  - gate: 16x256 matvec parallelized across all 256 threads (16-deep chains)
//  - GEMMs identical to round 8 (LDS-staged bf16 hi/lo MFMA).

#define CAP 128

typedef __attribute__((ext_vector_type(8))) short short8;
typedef __attribute__((ext_vector_type(4))) float floatx4;
typedef _Float16 half8 __attribute__((ext_vector_type(8)));
typedef _Float16 half4v __attribute__((ext_vector_type(4)));
#define MFMA16(a,b,c) __builtin_amdgcn_mfma_f32_16x16x32_bf16(a,b,c,0,0,0)
#define MFMAH(a,b,c)  __builtin_amdgcn_mfma_f32_16x16x32_f16(a,b,c,0,0,0)

// ---------- helpers ----------
__device__ __forceinline__ float umt(unsigned u){
  return __uint_as_float((u & 0x80000000u) ? (u & 0x7fffffffu) : ~u);
}
__device__ __forceinline__ float wmin_f(float v){
  #pragma unroll
  for (int m=1;m<64;m<<=1) v = fminf(v, __shfl_xor(v,m,64));
  return v;
}
__device__ __forceinline__ int mbcnt64(unsigned long long m){
  return (int)__builtin_amdgcn_mbcnt_hi((unsigned)(m>>32),
         __builtin_amdgcn_mbcnt_lo((unsigned)(m & 0xffffffffull), 0u));
}
__device__ __forceinline__ short8 ldb8(const __hip_bfloat16* p){
  return *(const short8*)p;
}
// convert 8 f32 -> bf16 hi/lo, write as two short8 (16B aligned LDS)
__device__ __forceinline__ void cvt8(short* dh, short* dl, float4 v0, float4 v1){
  const float vv[8] = {v0.x,v0.y,v0.z,v0.w,v1.x,v1.y,v1.z,v1.w};
  short8 h8, l8;
  #pragma unroll
  for (int i=0;i<8;i++){
    const __hip_bfloat16 h = __float2bfloat16(vv[i]);
    const __hip_bfloat16 l = __float2bfloat16(vv[i] - __bfloat162float(h));
    h8[i] = *(const short*)&h;
    l8[i] = *(const short*)&l;
  }
  *(short8*)dh = h8;
  *(short8*)dl = l8;
}

// full-register 20-bit bisection + v205 recovery (exact, used as rare fallback)
#define FULLSEL(SU, PSTART, V206, V205)                                        \
  {                                                                            \
    unsigned v = (PSTART);                                                     \
    _Pragma("unroll 1")                                                        \
    for (int bit = 19; bit >= 0; --bit){                                       \
      const float cf = umt(v | (1u << bit));                                   \
      int n = 0;                                                               \
      _Pragma("unroll")                                                        \
      for (int i = 0; i < 32; i++) n += (int)__popcll(__ballot(SU[i] >= cf));  \
      if (n >= 206) v |= (1u << bit);                                          \
    }                                                                          \
    V206 = umt(v);                                                             \
    int cgt = 0; float mn = 3.0e38f;                                           \
    _Pragma("unroll")                                                          \
    for (int i = 0; i < 32; i++){                                              \
      const float u = SU[i];                                                   \
      const bool gt = (u > V206);                                              \
      cgt += (int)__popcll(__ballot(gt));                                      \
      mn = (gt && u < mn) ? u : mn;                                            \
    }                                                                          \
    mn = wmin_f(mn);                                                           \
    V205 = (cgt == 205) ? mn : V206;                                           \
  }

// ---------- K0a: per-(b,16-row-chunk) column sums of x (512 blocks) ----------
__global__ void xpart_kernel(const float* __restrict__ x, float* __restrict__ xpart){
  const int ch = blockIdx.x, b = blockIdx.y, t = threadIdx.x;   // ch in [0,128)
  const float* xp = x + ((size_t)b*2048 + (size_t)ch*16)*256 + t;
  float s = 0.f;
  #pragma unroll
  for (int i=0;i<16;i++) s += xp[(size_t)i*256];
  xpart[(size_t)(b*128+ch)*256 + t] = s;
}

// ---------- K0b: gate[b][256], one block per batch, parallel matvec ----------
__global__ void gate_kernel(const float* __restrict__ xpart,
                            const float* __restrict__ Wg, const float* __restrict__ bg,
                            const float* __restrict__ Wgp,const float* __restrict__ bgp,
                            float* __restrict__ gate_ws){
  __shared__ float xm[256];
  __shared__ float part[16][17];
  __shared__ float g16[16];
  const int t = threadIdx.x;
  const int b = blockIdx.x;
  float s = 0.f;
  for (int ch=0; ch<128; ch++) s += xpart[(size_t)(b*128+ch)*256 + t];
  xm[t] = s * (1.0f/2048.0f);
  __syncthreads();
  // z[j] = bg[j] + sum_d xm[d]*Wg[j][d], parallel: j=t>>4, d-group=t&15
  {
    const int j = t >> 4, dg = t & 15;
    float p = 0.f;
    #pragma unroll
    for (int d=0; d<16; d++) p = fmaf(xm[dg*16+d], Wg[j*256 + dg*16 + d], p);
    part[j][dg] = p;
  }
  __syncthreads();
  if (t < 16){
    float z = bg[t];
    #pragma unroll
    for (int g=0; g<16; g++) z += part[t][g];
    g16[t] = 1.0f/(1.0f + __expf(-z));
  }
  __syncthreads();
  float z2 = bgp[t];
  #pragma unroll
  for (int j=0;j<16;j++) z2 = fmaf(g16[j], Wgp[t*16+j], z2);
  gate_ws[b*256 + t] = z2;
}

// ---------- K1: fused QKV projection, LDS-staged bf16 hi/lo MFMA ----------
// Q/K emitted as bf16 hi/lo; V emitted TRANSPOSED per (b,h): vth/vtl[(bh*64+hd)][s], f16 hi/lo.
__global__ __launch_bounds__(256) void qkv_gemm(
    const float* __restrict__ x,
    const float* __restrict__ Wq, const float* __restrict__ bq,
    const float* __restrict__ Wk, const float* __restrict__ bk,
    const float* __restrict__ Wv, const float* __restrict__ bv,
    __hip_bfloat16* __restrict__ qh, __hip_bfloat16* __restrict__ ql,
    __hip_bfloat16* __restrict__ kh, __hip_bfloat16* __restrict__ kl,
    _Float16* __restrict__ vth, _Float16* __restrict__ vtl){
  __shared__ short Ah[64][40], Al[64][40];   // 80B rows: 16B-aligned, bank stride 20
  __shared__ short Bh[64][40], Bl[64][40];
  const int m0 = blockIdx.x * 64;
  const int n0g = blockIdx.y * 64;          // global col tile in [0,768)
  const int sect = n0g >> 8;                // 0:Q 1:K 2:V
  const int nl0 = n0g & 255;
  const float* W    = (sect==0) ? Wq : ((sect==1) ? Wk : Wv);
  const float* bias = (sect==0) ? bq : ((sect==1) ? bk : bv);
  const int tid = threadIdx.x;
  const int lr = tid >> 2, lc = tid & 3;
  const int w = tid >> 6, ln = tid & 63;
  const int lm = ln & 15, lk = (ln >> 4) * 8;

  floatx4 acc[4];
  #pragma unroll
  for (int tl=0;tl<4;tl++) acc[tl] = (floatx4){0.f,0.f,0.f,0.f};

  for (int k0 = 0; k0 < 256; k0 += 32){
    const float4 a0 = *(const float4*)&x[(size_t)(m0 +lr)*256 + k0 + lc*8];
    const float4 a1 = *(const float4*)&x[(size_t)(m0 +lr)*256 + k0 + lc*8 + 4];
    const float4 b0 = *(const float4*)&W[(size_t)(nl0+lr)*256 + k0 + lc*8];
    const float4 b1 = *(const float4*)&W[(size_t)(nl0+lr)*256 + k0 + lc*8 + 4];
    __syncthreads();                       // previous iter frag reads done
    cvt8(&Ah[lr][lc*8], &Al[lr][lc*8], a0, a1);
    cvt8(&Bh[lr][lc*8], &Bl[lr][lc*8], b0, b1);
    __syncthreads();                       // staged tile visible
    const short8 ah8 = *(const short8*)&Ah[w*16+lm][lk];
    const short8 al8 = *(const short8*)&Al[w*16+lm][lk];
    #pragma unroll
    for (int tl = 0; tl < 4; tl++){
      const short8 bh8 = *(const short8*)&Bh[tl*16+lm][lk];
      const short8 bl8 = *(const short8*)&Bl[tl*16+lm][lk];
      acc[tl] = MFMA16(ah8, bh8, acc[tl]);
      acc[tl] = MFMA16(al8, bh8, acc[tl]);
      acc[tl] = MFMA16(ah8, bl8, acc[tl]);
      acc[tl] = MFMA16(al8, bl8, acc[tl]);
    }
  }

  // D layout: row = (ln>>4)*4 + i (M), col = ln&15 (N)
  #pragma unroll
  for (int tl = 0; tl < 4; tl++){
    const int f = nl0 + tl*16 + lm;        // feature in [0,256)
    const int hh = f >> 6, hd = f & 63;
    const float bf = bias[f];
    if (sect == 2){
      const int mB = m0 + w*16 + (ln >> 4)*4;  // 4 consecutive s values
      const int bidx = mB >> 11, s0 = mB & 2047;
      half4v hv, lv;
      #pragma unroll
      for (int i=0;i<4;i++){
        const float val = acc[tl][i] + bf;
        const _Float16 hx = (_Float16)val;
        hv[i] = hx;
        lv[i] = (_Float16)(val - (float)hx);
      }
      const size_t row = (size_t)((bidx*4+hh)*64 + hd);
      *(half4v*)(vth + row*2048 + s0) = hv;
      *(half4v*)(vtl + row*2048 + s0) = lv;
    } else {
      #pragma unroll
      for (int i=0;i<4;i++){
        const int m = m0 + w*16 + (ln >> 4)*4 + i;
        const int bidx = m >> 11, s = m & 2047;
        const float val = acc[tl][i] + bf;
        const size_t idx = (size_t)((bidx*4+hh)*2048 + s)*64 + hd;
        const __hip_bfloat16 hi = __float2bfloat16(val);
        const float lo = val - __bfloat162float(hi);
        if (sect == 0){ qh[idx] = hi; ql[idx] = __float2bfloat16(lo); }
        else          { kh[idx] = hi; kl[idx] = __float2bfloat16(lo); }
      }
    }
  }
}

// ---------- K2: sparse attention + fused distill/gate mix ----------
// smem phases:
//  1: two ping-pong score handoff buffers [16][516] f32 (66 KB)
//  2: per-(wave,row) cand scratch at [65536 + (2w+rr)*512), 8 KB total
//  3: _Float16 pbuf[16][2048] probs in [0,64K), byte bits 4-6 XOR (row&7)<<4
__global__ __launch_bounds__(512, 4) void attn_kernel(
    const __hip_bfloat16* __restrict__ qh, const __hip_bfloat16* __restrict__ ql,
    const __hip_bfloat16* __restrict__ kh, const __hip_bfloat16* __restrict__ kl,
    const _Float16* __restrict__ vth, const _Float16* __restrict__ vtl,
    const float* __restrict__ Wd, const float* __restrict__ bd,
    const float* __restrict__ gate_ws, float* __restrict__ mix_ws){
  __shared__ __align__(16) char smem[74240];
  __shared__ float obuf[16][66];   // cross-half PV reduce (stride 66: conflict-free)
  __shared__ float zbuf[16];       // 1/Z per row

  float (*buf0)[516] = (float (*)[516])smem;
  float (*buf1)[516] = (float (*)[516])(smem + 33024);

  const int bh = blockIdx.y;
  const int q0 = blockIdx.x * 16;
  const int tid = threadIdx.x;
  const int w = tid >> 6, ln = tid & 63;
  const int lm = ln & 15;
  const int lk = (ln >> 4) * 8;
  const int qa = 2*w, qb = 2*w + 1;

  const __hip_bfloat16* Qh = qh + ((size_t)bh*2048 + q0)*64;
  const __hip_bfloat16* Ql = ql + ((size_t)bh*2048 + q0)*64;
  const __hip_bfloat16* Kh = kh + ((size_t)bh*2048 + w*256)*64;
  const __hip_bfloat16* Kl = kl + ((size_t)bh*2048 + w*256)*64;

  float su0[32], su1[32];

  // ----- rounds: MFMA 4 tiles -> ping-pong LDS handoff (1 barrier/chunk) -----
  // Q fragments reloaded per chunk (L1/L2-hot, 4 KB/block): keeps score-phase
  // register peak < 128 so su[] stays in arch VGPRs (no accvgpr bounces).
  #pragma unroll
  for (int c = 0; c < 4; c++){
    float (*bufc)[516] = (c & 1) ? buf1 : buf0;
    const short8 ah0 = ldb8(Qh + lm*64 + lk);
    const short8 ah1 = ldb8(Qh + lm*64 + 32 + lk);
    const short8 al0 = ldb8(Ql + lm*64 + lk);
    const short8 al1 = ldb8(Ql + lm*64 + 32 + lk);
    floatx4 acc[4];
    #pragma unroll
    for (int tl = 0; tl < 4; tl++){
      const int krow = c*64 + tl*16 + lm;
      short8 bh0 = ldb8(Kh + krow*64 + lk);
      short8 bh1 = ldb8(Kh + krow*64 + 32 + lk);
      short8 bl0 = ldb8(Kl + krow*64 + lk);
      short8 bl1 = ldb8(Kl + krow*64 + 32 + lk);
      floatx4 a = {0.f,0.f,0.f,0.f};
      a = MFMA16(ah0, bh0, a);
      a = MFMA16(ah1, bh1, a);
      a = MFMA16(al0, bh0, a);
      a = MFMA16(al1, bh1, a);
      a = MFMA16(ah0, bl0, a);
      a = MFMA16(ah1, bl1, a);
      a = MFMA16(al0, bl0, a);
      a = MFMA16(al1, bl1, a);
      acc[tl] = a;
    }
    const int wr = (ln >> 4) * 4;         // C-layout: row=(lane>>4)*4+reg, col=lane&15
    #pragma unroll
    for (int tl = 0; tl < 4; tl++){
      const int col = w*64 + tl*16 + lm;
      bufc[wr+0][col] = acc[tl].x * 0.125f;
      bufc[wr+1][col] = acc[tl].y * 0.125f;
      bufc[wr+2][col] = acc[tl].z * 0.125f;
      bufc[wr+3][col] = acc[tl].w * 0.125f;
    }
    __syncthreads();                      // chunk c visible; c-1 readers all done
    float4 ra0 = *(const float4*)&bufc[qa][4*ln];
    float4 ra1 = *(const float4*)&bufc[qa][256 + 4*ln];
    float4 rb0 = *(const float4*)&bufc[qb][4*ln];
    float4 rb1 = *(const float4*)&bufc[qb][256 + 4*ln];
    const int o = c*8;
    su0[o+0]=ra0.x; su0[o+1]=ra0.y; su0[o+2]=ra0.z; su0[o+3]=ra0.w;
    su0[o+4]=ra1.x; su0[o+5]=ra1.y; su0[o+6]=ra1.z; su0[o+7]=ra1.w;
    su1[o+0]=rb0.x; su1[o+1]=rb0.y; su1[o+2]=rb0.z; su1[o+3]=rb0.w;
    su1[o+4]=rb1.x; su1[o+5]=rb1.y; su1[o+6]=rb1.z; su1[o+7]=rb1.w;
  }
  __syncthreads();   // bufs dead; smem may now be reused for cand/probs
  // su index i (chunk c=i>>3, m=i&7) -> key:
  //   key = (ln>>4)*256 + ((m&4)<<8) + c*64 + (ln&15)*4 + (m&3)

  // ----- level-1: bisect top 12 bits (row0 VALU+shfl, row1 ballot/SALU) -----
  unsigned p0 = 0, p1 = 0;
  #pragma unroll 1
  for (int bit = 31; bit >= 20; --bit){
    const float c0f = umt(p0 | (1u << bit));
    const float c1f = umt(p1 | (1u << bit));
    int v0 = 0, n1 = 0;
    #pragma unroll
    for (int i = 0; i < 32; i++){
      v0 += (su0[i] >= c0f) ? 1 : 0;                      // VALU per-lane
      n1 += (int)__popcll(__ballot(su1[i] >= c1f));       // SALU count
    }
    #pragma unroll
    for (int m=1;m<64;m<<=1) v0 += __shfl_xor(v0,m,64);   // DS reduce (row0)
    p0 |= (v0 >= 206) ? (1u << bit) : 0u;
    if (n1 >= 206) p1 |= (1u << bit);
  }

  const int b = bh >> 2, h = bh & 3;

  // ----- both rows interleaved: scan, bisect, v205, probs, Z -----
  const float pf0  = umt(p0),             pf1  = umt(p1);
  const float hif0 = umt(p0 + 0x100000u), hif1 = umt(p1 + 0x100000u);
  float* cand0 = (float*)(smem + 65536 + (size_t)(2*w + 0)*512);
  float* cand1 = (float*)(smem + 65536 + (size_t)(2*w + 1)*512);

  int above0 = 0, nc0 = 0, above1 = 0, nc1 = 0;
  float mx0 = -3.0e38f, mx1 = -3.0e38f, mnab0 = 3.0e38f, mnab1 = 3.0e38f;
  #pragma unroll
  for (int i = 0; i < 32; i++){
    const float u0 = su0[i], u1 = su1[i];
    mx0 = fmaxf(mx0, u0);
    mx1 = fmaxf(mx1, u1);
    const bool ab0 = (u0 >= hif0), ab1 = (u1 >= hif1);
    above0 += ab0 ? 1 : 0;                 // VALU per-lane
    above1 += ab1 ? 1 : 0;
    if (ab0) mnab0 = fminf(mnab0, u0);
    if (ab1) mnab1 = fminf(mnab1, u1);
    const bool cd0 = (u0 >= pf0) && !ab0, cd1 = (u1 >= pf1) && !ab1;
    const unsigned long long bal0 = __ballot(cd0);
    if (cd0){
      const int pos = nc0 + mbcnt64(bal0);
      if (pos < CAP) cand0[pos] = u0;
    }
    nc0 += (int)__popcll(bal0);
    const unsigned long long bal1 = __ballot(cd1);
    if (cd1){
      const int pos = nc1 + mbcnt64(bal1);
      if (pos < CAP) cand1[pos] = u1;
    }
    nc1 += (int)__popcll(bal1);
  }
  int ab01 = above0 | (above1 << 16);      // packed cross-lane reduce
  #pragma unroll
  for (int m=1;m<64;m<<=1){
    ab01  += __shfl_xor(ab01, m,64);
    mx0   = fmaxf(mx0,   __shfl_xor(mx0,  m,64));
    mx1   = fmaxf(mx1,   __shfl_xor(mx1,  m,64));
    mnab0 = fminf(mnab0, __shfl_xor(mnab0,m,64));
    mnab1 = fminf(mnab1, __shfl_xor(mnab1,m,64));
  }
  above0 = ab01 & 0xffff;
  above1 = ab01 >> 16;

  float v206_0, v205_0, v206_1, v205_1;
  if (__builtin_expect(nc0 <= CAP && nc1 <= CAP, 1)){
    const int j0 = 206 - above0, j1 = 206 - above1;
    const float cv00 = (ln      < nc0) ? cand0[ln]      : -3.0e38f;
    const float cv01 = (ln + 64 < nc0) ? cand0[ln + 64] : -3.0e38f;
    const float cv10 = (ln      < nc1) ? cand1[ln]      : -3.0e38f;
    const float cv11 = (ln + 64 < nc1) ? cand1[ln + 64] : -3.0e38f;
    unsigned v0 = p0, v1 = p1;
    #pragma unroll 1
    for (int bit = 19; bit >= 0; --bit){
      const float cf0 = umt(v0 | (1u << bit));
      const float cf1 = umt(v1 | (1u << bit));
      const int n0 = (int)__popcll(__ballot(cv00 >= cf0))
                   + (int)__popcll(__ballot(cv01 >= cf0));
      const int n1 = (int)__popcll(__ballot(cv10 >= cf1))
                   + (int)__popcll(__ballot(cv11 >= cf1));
      if (n0 >= j0) v0 |= (1u << bit);
      if (n1 >= j1) v1 |= (1u << bit);
    }
    v206_0 = umt(v0);
    v206_1 = umt(v1);
    const int cgtc0 = (int)__popcll(__ballot(cv00 > v206_0))
                    + (int)__popcll(__ballot(cv01 > v206_0));
    const int cgtc1 = (int)__popcll(__ballot(cv10 > v206_1))
                    + (int)__popcll(__ballot(cv11 > v206_1));
    float mnc0 = 3.0e38f, mnc1 = 3.0e38f;
    if (cv00 > v206_0) mnc0 = fminf(mnc0, cv00);
    if (cv01 > v206_0) mnc0 = fminf(mnc0, cv01);
    if (cv10 > v206_1) mnc1 = fminf(mnc1, cv10);
    if (cv11 > v206_1) mnc1 = fminf(mnc1, cv11);
    #pragma unroll
    for (int m=1;m<64;m<<=1){
      mnc0 = fminf(mnc0, __shfl_xor(mnc0,m,64));
      mnc1 = fminf(mnc1, __shfl_xor(mnc1,m,64));
    }
    const int cgt0 = above0 + cgtc0, cgt1 = above1 + cgtc1;
    v205_0 = (cgt0 == 205) ? ((cgtc0 > 0) ? mnc0 : mnab0) : v206_0;
    v205_1 = (cgt1 == 205) ? ((cgtc1 > 0) ? mnc1 : mnab1) : v206_1;
  } else {
    FULLSEL(su0, p0, v206_0, v205_0);
    FULLSEL(su1, p1, v206_1, v205_1);
  }

  const float thr0 = (float)((double)v206_0 + 0.3*((double)v205_0 - (double)v206_0));
  const float thr1 = (float)((double)v206_1 + 0.3*((double)v205_1 - (double)v206_1));

  // dense probs, both rows fused: p = s>=thr ? exp(s-mx) : 0 -> f16 pbuf
  float zl0 = 0.f, zl1 = 0.f;
  char* rba = smem + (size_t)qa*4096 + ((size_t)(ln >> 4) << 9)
            + (size_t)((((ln & 15) << 3)) ^ ((qa & 7) << 4));
  char* rbb = smem + (size_t)qb*4096 + ((size_t)(ln >> 4) << 9)
            + (size_t)((((ln & 15) << 3)) ^ ((qb & 7) << 4));
  #pragma unroll
  for (int c = 0; c < 4; c++){
    #pragma unroll
    for (int h4 = 0; h4 < 2; h4++){
      half4v pk0, pk1;
      #pragma unroll
      for (int jj = 0; jj < 4; jj++){
        const int i = c*8 + h4*4 + jj;
        const float s0 = su0[i], s1 = su1[i];
        const float pr0 = (s0 >= thr0) ? __expf(s0 - mx0) : 0.f;
        const float pr1 = (s1 >= thr1) ? __expf(s1 - mx1) : 0.f;
        const _Float16 ph0 = (_Float16)pr0;
        const _Float16 ph1 = (_Float16)pr1;
        zl0 += (float)ph0;                // Z from f16-rounded p for consistency
        zl1 += (float)ph1;
        pk0[jj] = ph0;
        pk1[jj] = ph1;
      }
      *(half4v*)(rba + h4*2048 + c*128) = pk0;
      *(half4v*)(rbb + h4*2048 + c*128) = pk1;
    }
  }
  #pragma unroll
  for (int m=1;m<64;m<<=1){
    zl0 += __shfl_xor(zl0,m,64);
    zl1 += __shfl_xor(zl1,m,64);
  }
  if (ln == 0){ zbuf[qa] = 1.0f / zl0; zbuf[qb] = 1.0f / zl1; }

  __syncthreads();   // all pbuf rows + zbuf visible

  // ----- PV: out[16x64] = P[16x2048] @ V[2048x64], f16 MFMA -----
  const int ct = w & 3, kh2 = w >> 2;
  const int arow = ln & 15;
  const int sw = (arow & 7) << 4;       // involution on byte bits 4-6
  const char* prow = smem + (size_t)arow*4096;
  const int klog0 = (kh2 << 11) + ((ln >> 4) << 4);
  const _Float16* vhp = vth + ((size_t)bh*64 + ct*16 + arow)*2048 + (kh2 << 10) + ((ln >> 4) << 3);
  const _Float16* vlp = vtl + ((size_t)bh*64 + ct*16 + arow)*2048 + (kh2 << 10) + ((ln >> 4) << 3);

  floatx4 acch = {0.f,0.f,0.f,0.f};
  floatx4 accl = {0.f,0.f,0.f,0.f};
  #pragma unroll 4
  for (int kk = 0; kk < 32; kk++){
    const half8 a   = *(const half8*)(prow + ((klog0 + kk*64) ^ sw));
    const half8 vh8 = *(const half8*)(vhp + kk*32);
    const half8 vl8 = *(const half8*)(vlp + kk*32);
    acch = MFMAH(a, vh8, acch);
    accl = MFMAH(a, vl8, accl);
  }
  floatx4 acc = acch + accl;

  // distill params for kh2==0 waves (loads overlap the obuf barrier)
  float gt = 0.f, bda = 0.f;
  float wdv[16];
  if (kh2 == 1){
    const int r0 = (ln >> 4) * 4;
    #pragma unroll
    for (int i = 0; i < 4; i++) obuf[r0+i][ct*16 + arow] = acc[i];
  } else {
    gt  = gate_ws[(size_t)b*256 + h*64 + ct*16 + arow];
    bda = bd[arow];
    #pragma unroll
    for (int m4 = 0; m4 < 4; m4++){
      const float4 t4 = *(const float4*)&Wd[arow*16 + m4*4];
      wdv[m4*4+0]=t4.x; wdv[m4*4+1]=t4.y; wdv[m4*4+2]=t4.z; wdv[m4*4+3]=t4.w;
    }
  }
  __syncthreads();
  if (kh2 == 0){
    const int r0 = (ln >> 4) * 4;
    const int gb = ln & 48;              // 16-lane group base = distill group
    #pragma unroll
    for (int i = 0; i < 4; i++){
      const int r = r0 + i;
      const float o = (acc[i] + obuf[r][ct*16 + arow]) * zbuf[r];
      float d = bda;
      #pragma unroll
      for (int m = 0; m < 16; m++)
        d = fmaf(__shfl(o, gb + m, 64), wdv[m], d);
      const float mixed = gt*d + (1.0f - gt)*o;
      mix_ws[(size_t)(b*2048 + q0 + r)*256 + h*64 + ct*16 + arow] = mixed;
    }
  }
}

// ---------- K4: out = mixed @ Wo^T + bo, LDS-staged bf16 hi/lo MFMA ----------
__global__ __launch_bounds__(256) void out_gemm(
    const float* __restrict__ A, const float* __restrict__ Wo,
    const float* __restrict__ bo, float* __restrict__ out){
  __shared__ short Ah[64][40], Al[64][40];
  __shared__ short Bh[64][40], Bl[64][40];
  const int m0 = blockIdx.x * 64;
  const int n0 = blockIdx.y * 64;
  const int tid = threadIdx.x;
  const int lr = tid >> 2, lc = tid & 3;
  const int w = tid >> 6, ln = tid & 63;
  const int lm = ln & 15, lk = (ln >> 4) * 8;

  floatx4 acc[4];
  #pragma unroll
  for (int tl=0;tl<4;tl++) acc[tl] = (floatx4){0.f,0.f,0.f,0.f};

  for (int k0 = 0; k0 < 256; k0 += 32){
    const float4 a0 = *(const float4*)&A [(size_t)(m0+lr)*256 + k0 + lc*8];
    const float4 a1 = *(const float4*)&A [(size_t)(m0+lr)*256 + k0 + lc*8 + 4];
    const float4 b0 = *(const float4*)&Wo[(size_t)(n0+lr)*256 + k0 + lc*8];
    const float4 b1 = *(const float4*)&Wo[(size_t)(n0+lr)*256 + k0 + lc*8 + 4];
    __syncthreads();
    cvt8(&Ah[lr][lc*8], &Al[lr][lc*8], a0, a1);
    cvt8(&Bh[lr][lc*8], &Bl[lr][lc*8], b0, b1);
    __syncthreads();
    const short8 ah8 = *(const short8*)&Ah[w*16+lm][lk];
    const short8 al8 = *(const short8*)&Al[w*16+lm][lk];
    #pragma unroll
    for (int tl = 0; tl < 4; tl++){
      const short8 bh8 = *(const short8*)&Bh[tl*16+lm][lk];
      const short8 bl8 = *(const short8*)&Bl[tl*16+lm][lk];
      acc[tl] = MFMA16(ah8, bh8, acc[tl]);
      acc[tl] = MFMA16(al8, bh8, acc[tl]);
      acc[tl] = MFMA16(ah8, bl8, acc[tl]);
      acc[tl] = MFMA16(al8, bl8, acc[tl]);
    }
  }

  #pragma unroll
  for (int tl = 0; tl < 4; tl++){
    const int f = n0 + tl*16 + lm;
    const float bf = bo[f];
    #pragma unroll
    for (int i=0;i<4;i++){
      const int m = m0 + w*16 + (ln >> 4)*4 + i;
      out[(size_t)m*256 + f] = acc[tl][i] + bf;
    }
  }
}

// ---------- launch ----------
extern "C" void kernel_launch(void* const* d_in, const int* in_sizes, int n_in,
                              void* d_out, int out_size, void* d_ws, size_t ws_size,
                              hipStream_t stream) {
  const float* x   = (const float*)d_in[0];
  const float* Wq  = (const float*)d_in[1];  const float* bq  = (const float*)d_in[2];
  const float* Wk  = (const float*)d_in[3];  const float* bk  = (const float*)d_in[4];
  const float* Wv  = (const float*)d_in[5];  const float* bv  = (const float*)d_in[6];
  const float* Wd  = (const float*)d_in[7];  const float* bd  = (const float*)d_in[8];
  const float* Wg  = (const float*)d_in[9];  const float* bg  = (const float*)d_in[10];
  const float* Wgp = (const float*)d_in[11]; const float* bgp = (const float*)d_in[12];
  const float* Wo  = (const float*)d_in[13]; const float* bo  = (const float*)d_in[14];

  char* base = (char*)d_ws;
  float* mix_ws = (float*)(base);                       // 8 MB
  __hip_bfloat16* qh = (__hip_bfloat16*)(base + (size_t)( 8<<20));  // 4 MB
  __hip_bfloat16* ql = (__hip_bfloat16*)(base + (size_t)(12<<20));  // 4 MB
  __hip_bfloat16* kh = (__hip_bfloat16*)(base + (size_t)(16<<20));  // 4 MB
  __hip_bfloat16* kl = (__hip_bfloat16*)(base + (size_t)(20<<20));  // 4 MB
  _Float16* vth = (_Float16*)(base + (size_t)(24<<20));             // 4 MB (V^T hi)
  _Float16* vtl = (_Float16*)(base + (size_t)(28<<20));             // 4 MB (V^T lo)
  float* xpart  = (float*)(base + (size_t)(32<<20));    // 512 KB
  float* gate_ws= (float*)(base + (size_t)(33<<20));

  xpart_kernel<<<dim3(128,4), 256, 0, stream>>>(x, xpart);
  gate_kernel<<<4, 256, 0, stream>>>(xpart, Wg, bg, Wgp, bgp, gate_ws);
  qkv_gemm<<<dim3(128,12), 256, 0, stream>>>(x, Wq,bq, Wk,bk, Wv,bv,
                                             qh, ql, kh, kl, vth, vtl);
  attn_kernel<<<dim3(128,16), 512, 0, stream>>>(qh, ql, kh, kl, vth, vtl,
                                                Wd, bd, gate_ws, mix_ws);
  out_gemm<<<dim3(128,4), 256, 0, stream>>>(mix_ws, Wo, bo, (float*)d_out);
}

// Round 11
// 405.813 us; speedup vs baseline: 1.0243x; 1.0243x over previous
//
#include <hip/hip_runtime.h>
#include <hip/hip_bf16.h>
#include <math.h>

// B=4, S=2048, D=256, H=4, HD=64; keep top-10% per score row.
// thr = v206 + 0.3*(v205 - v206)  (v_k = k-th largest), exact via bit-bisection.
//
// Round-10 occupancy plan, with the LDS-overflow bug fixed:
//  BUG WAS: cand scratch = 16 buffers x 512B = 8192B placed at smem+33024 in a
//  37312B array -> waves 4-7 wrote out of bounds (absmax 3.5e-2).
//  FIX: cand lives in the DEAD score-buffer region [0,8192) (wave-private),
//  with one extra barrier between selection and the P-half writes that reuse
//  that region. LDS stays 37312B => 4 blocks/CU (was 2), doubling resident
//  waves for the latency-chain-bound attn kernel.
//  smem map:
//   [0, 33024)      phase 1: score handoff buf [16][516] f32
//                   phase 2: cand scratch (16 x 512B at w*1024+rr*512)
//                   phase 3: P-half [16][1024] f16 (32KB), swz bits4-6 ^(row&7)<<4
//   [33024, 37248)  phase 4: obuf[16][66] cross-quarter PV reduce
//   [37248, 37312)  zbuf[16]

#define CAP 128

typedef __attribute__((ext_vector_type(8))) short short8;
typedef __attribute__((ext_vector_type(4))) float floatx4;
typedef _Float16 half8 __attribute__((ext_vector_type(8)));
typedef _Float16 half4v __attribute__((ext_vector_type(4)));
#define MFMA16(a,b,c) __builtin_amdgcn_mfma_f32_16x16x32_bf16(a,b,c,0,0,0)
#define MFMAH(a,b,c)  __builtin_amdgcn_mfma_f32_16x16x32_f16(a,b,c,0,0,0)

// ---------- helpers ----------
__device__ __forceinline__ float umt(unsigned u){
  return __uint_as_float((u & 0x80000000u) ? (u & 0x7fffffffu) : ~u);
}
__device__ __forceinline__ float wmin_f(float v){
  #pragma unroll
  for (int m=1;m<64;m<<=1) v = fminf(v, __shfl_xor(v,m,64));
  return v;
}
__device__ __forceinline__ int mbcnt64(unsigned long long m){
  return (int)__builtin_amdgcn_mbcnt_hi((unsigned)(m>>32),
         __builtin_amdgcn_mbcnt_lo((unsigned)(m & 0xffffffffull), 0u));
}
__device__ __forceinline__ short8 ldb8(const __hip_bfloat16* p){
  return *(const short8*)p;
}
// convert 8 f32 -> bf16 hi/lo, write as two short8 (16B aligned LDS)
__device__ __forceinline__ void cvt8(short* dh, short* dl, float4 v0, float4 v1){
  const float vv[8] = {v0.x,v0.y,v0.z,v0.w,v1.x,v1.y,v1.z,v1.w};
  short8 h8, l8;
  #pragma unroll
  for (int i=0;i<8;i++){
    const __hip_bfloat16 h = __float2bfloat16(vv[i]);
    const __hip_bfloat16 l = __float2bfloat16(vv[i] - __bfloat162float(h));
    h8[i] = *(const short*)&h;
    l8[i] = *(const short*)&l;
  }
  *(short8*)dh = h8;
  *(short8*)dl = l8;
}

// full-register 20-bit bisection + v205 recovery (exact, used as rare fallback)
#define FULLSEL(SU, PSTART, V206, V205)                                        \
  {                                                                            \
    unsigned v = (PSTART);                                                     \
    _Pragma("unroll 1")                                                        \
    for (int bit = 19; bit >= 0; --bit){                                       \
      const float cf = umt(v | (1u << bit));                                   \
      int n = 0;                                                               \
      _Pragma("unroll")                                                        \
      for (int i = 0; i < 32; i++) n += (int)__popcll(__ballot(SU[i] >= cf));  \
      if (n >= 206) v |= (1u << bit);                                          \
    }                                                                          \
    V206 = umt(v);                                                             \
    int cgt = 0; float mn = 3.0e38f;                                           \
    _Pragma("unroll")                                                          \
    for (int i = 0; i < 32; i++){                                              \
      const float u = SU[i];                                                   \
      const bool gt = (u > V206);                                              \
      cgt += (int)__popcll(__ballot(gt));                                      \
      mn = (gt && u < mn) ? u : mn;                                            \
    }                                                                          \
    mn = wmin_f(mn);                                                           \
    V205 = (cgt == 205) ? mn : V206;                                           \
  }

// ---------- K0a: per-(b,16-row-chunk) column sums of x (512 blocks) ----------
__global__ void xpart_kernel(const float* __restrict__ x, float* __restrict__ xpart){
  const int ch = blockIdx.x, b = blockIdx.y, t = threadIdx.x;   // ch in [0,128)
  const float* xp = x + ((size_t)b*2048 + (size_t)ch*16)*256 + t;
  float s = 0.f;
  #pragma unroll
  for (int i=0;i<16;i++) s += xp[(size_t)i*256];
  xpart[(size_t)(b*128+ch)*256 + t] = s;
}

// ---------- K0b: gate[b][256], one block per batch, parallel matvec ----------
__global__ void gate_kernel(const float* __restrict__ xpart,
                            const float* __restrict__ Wg, const float* __restrict__ bg,
                            const float* __restrict__ Wgp,const float* __restrict__ bgp,
                            float* __restrict__ gate_ws){
  __shared__ float xm[256];
  __shared__ float part[16][17];
  __shared__ float g16[16];
  const int t = threadIdx.x;
  const int b = blockIdx.x;
  float s = 0.f;
  for (int ch=0; ch<128; ch++) s += xpart[(size_t)(b*128+ch)*256 + t];
  xm[t] = s * (1.0f/2048.0f);
  __syncthreads();
  {
    const int j = t >> 4, dg = t & 15;
    float p = 0.f;
    #pragma unroll
    for (int d=0; d<16; d++) p = fmaf(xm[dg*16+d], Wg[j*256 + dg*16 + d], p);
    part[j][dg] = p;
  }
  __syncthreads();
  if (t < 16){
    float z = bg[t];
    #pragma unroll
    for (int g=0; g<16; g++) z += part[t][g];
    g16[t] = 1.0f/(1.0f + __expf(-z));
  }
  __syncthreads();
  float z2 = bgp[t];
  #pragma unroll
  for (int j=0;j<16;j++) z2 = fmaf(g16[j], Wgp[t*16+j], z2);
  gate_ws[b*256 + t] = z2;
}

// ---------- K1: fused QKV projection, LDS-staged bf16 hi/lo MFMA ----------
__global__ __launch_bounds__(256) void qkv_gemm(
    const float* __restrict__ x,
    const float* __restrict__ Wq, const float* __restrict__ bq,
    const float* __restrict__ Wk, const float* __restrict__ bk,
    const float* __restrict__ Wv, const float* __restrict__ bv,
    __hip_bfloat16* __restrict__ qh, __hip_bfloat16* __restrict__ ql,
    __hip_bfloat16* __restrict__ kh, __hip_bfloat16* __restrict__ kl,
    _Float16* __restrict__ vth, _Float16* __restrict__ vtl){
  __shared__ short Ah[64][40], Al[64][40];   // 80B rows: 16B-aligned, bank stride 20
  __shared__ short Bh[64][40], Bl[64][40];
  const int m0 = blockIdx.x * 64;
  const int n0g = blockIdx.y * 64;          // global col tile in [0,768)
  const int sect = n0g >> 8;                // 0:Q 1:K 2:V
  const int nl0 = n0g & 255;
  const float* W    = (sect==0) ? Wq : ((sect==1) ? Wk : Wv);
  const float* bias = (sect==0) ? bq : ((sect==1) ? bk : bv);
  const int tid = threadIdx.x;
  const int lr = tid >> 2, lc = tid & 3;
  const int w = tid >> 6, ln = tid & 63;
  const int lm = ln & 15, lk = (ln >> 4) * 8;

  floatx4 acc[4];
  #pragma unroll
  for (int tl=0;tl<4;tl++) acc[tl] = (floatx4){0.f,0.f,0.f,0.f};

  for (int k0 = 0; k0 < 256; k0 += 32){
    const float4 a0 = *(const float4*)&x[(size_t)(m0 +lr)*256 + k0 + lc*8];
    const float4 a1 = *(const float4*)&x[(size_t)(m0 +lr)*256 + k0 + lc*8 + 4];
    const float4 b0 = *(const float4*)&W[(size_t)(nl0+lr)*256 + k0 + lc*8];
    const float4 b1 = *(const float4*)&W[(size_t)(nl0+lr)*256 + k0 + lc*8 + 4];
    __syncthreads();                       // previous iter frag reads done
    cvt8(&Ah[lr][lc*8], &Al[lr][lc*8], a0, a1);
    cvt8(&Bh[lr][lc*8], &Bl[lr][lc*8], b0, b1);
    __syncthreads();                       // staged tile visible
    const short8 ah8 = *(const short8*)&Ah[w*16+lm][lk];
    const short8 al8 = *(const short8*)&Al[w*16+lm][lk];
    #pragma unroll
    for (int tl = 0; tl < 4; tl++){
      const short8 bh8 = *(const short8*)&Bh[tl*16+lm][lk];
      const short8 bl8 = *(const short8*)&Bl[tl*16+lm][lk];
      acc[tl] = MFMA16(ah8, bh8, acc[tl]);
      acc[tl] = MFMA16(al8, bh8, acc[tl]);
      acc[tl] = MFMA16(ah8, bl8, acc[tl]);
      acc[tl] = MFMA16(al8, bl8, acc[tl]);
    }
  }

  #pragma unroll
  for (int tl = 0; tl < 4; tl++){
    const int f = nl0 + tl*16 + lm;        // feature in [0,256)
    const int hh = f >> 6, hd = f & 63;
    const float bf = bias[f];
    if (sect == 2){
      const int mB = m0 + w*16 + (ln >> 4)*4;  // 4 consecutive s values
      const int bidx = mB >> 11, s0 = mB & 2047;
      half4v hv, lv;
      #pragma unroll
      for (int i=0;i<4;i++){
        const float val = acc[tl][i] + bf;
        const _Float16 hx = (_Float16)val;
        hv[i] = hx;
        lv[i] = (_Float16)(val - (float)hx);
      }
      const size_t row = (size_t)((bidx*4+hh)*64 + hd);
      *(half4v*)(vth + row*2048 + s0) = hv;
      *(half4v*)(vtl + row*2048 + s0) = lv;
    } else {
      #pragma unroll
      for (int i=0;i<4;i++){
        const int m = m0 + w*16 + (ln >> 4)*4 + i;
        const int bidx = m >> 11, s = m & 2047;
        const float val = acc[tl][i] + bf;
        const size_t idx = (size_t)((bidx*4+hh)*2048 + s)*64 + hd;
        const __hip_bfloat16 hi = __float2bfloat16(val);
        const float lo = val - __bfloat162float(hi);
        if (sect == 0){ qh[idx] = hi; ql[idx] = __float2bfloat16(lo); }
        else          { kh[idx] = hi; kl[idx] = __float2bfloat16(lo); }
      }
    }
  }
}

// ---------- K2: sparse attention + fused distill/gate mix ----------
__global__ __launch_bounds__(512, 4) void attn_kernel(
    const __hip_bfloat16* __restrict__ qh, const __hip_bfloat16* __restrict__ ql,
    const __hip_bfloat16* __restrict__ kh, const __hip_bfloat16* __restrict__ kl,
    const _Float16* __restrict__ vth, const _Float16* __restrict__ vtl,
    const float* __restrict__ Wd, const float* __restrict__ bd,
    const float* __restrict__ gate_ws, float* __restrict__ mix_ws){
  __shared__ __align__(16) char smem[37312];
  float (*buf)[516] = (float (*)[516])smem;
  float (*obuf)[66] = (float (*)[66])(smem + 33024);
  float* zbuf = (float*)(smem + 37248);

  const int bh = blockIdx.y;
  const int q0 = blockIdx.x * 16;
  const int tid = threadIdx.x;
  const int w = tid >> 6, ln = tid & 63;
  const int lm = ln & 15;
  const int lk = (ln >> 4) * 8;
  const int qa = 2*w, qb = 2*w + 1;

  const __hip_bfloat16* Qh = qh + ((size_t)bh*2048 + q0)*64;
  const __hip_bfloat16* Ql = ql + ((size_t)bh*2048 + q0)*64;
  const __hip_bfloat16* Kh = kh + ((size_t)bh*2048 + w*256)*64;
  const __hip_bfloat16* Kl = kl + ((size_t)bh*2048 + w*256)*64;

  float su0[32], su1[32];

  // Q fragments are chunk-invariant: hoist.
  const short8 ah0 = ldb8(Qh + lm*64 + lk);
  const short8 ah1 = ldb8(Qh + lm*64 + 32 + lk);
  const short8 al0 = ldb8(Ql + lm*64 + lk);
  const short8 al1 = ldb8(Ql + lm*64 + 32 + lk);

  // ----- rounds: MFMA 4 tiles -> single-buffer LDS handoff (2 barriers/chunk) -----
  #pragma unroll
  for (int c = 0; c < 4; c++){
    floatx4 acc[4];
    #pragma unroll
    for (int tl = 0; tl < 4; tl++){
      const int krow = c*64 + tl*16 + lm;
      short8 bh0 = ldb8(Kh + krow*64 + lk);
      short8 bh1 = ldb8(Kh + krow*64 + 32 + lk);
      short8 bl0 = ldb8(Kl + krow*64 + lk);
      short8 bl1 = ldb8(Kl + krow*64 + 32 + lk);
      floatx4 a = {0.f,0.f,0.f,0.f};
      a = MFMA16(ah0, bh0, a);
      a = MFMA16(ah1, bh1, a);
      a = MFMA16(al0, bh0, a);
      a = MFMA16(al1, bh1, a);
      a = MFMA16(ah0, bl0, a);
      a = MFMA16(ah1, bl1, a);
      a = MFMA16(al0, bl0, a);
      a = MFMA16(al1, bl1, a);
      acc[tl] = a;
    }
    __syncthreads();                      // previous chunk fully read
    const int wr = (ln >> 4) * 4;         // C-layout: row=(lane>>4)*4+reg, col=lane&15
    #pragma unroll
    for (int tl = 0; tl < 4; tl++){
      const int col = w*64 + tl*16 + lm;
      buf[wr+0][col] = acc[tl].x * 0.125f;
      buf[wr+1][col] = acc[tl].y * 0.125f;
      buf[wr+2][col] = acc[tl].z * 0.125f;
      buf[wr+3][col] = acc[tl].w * 0.125f;
    }
    __syncthreads();                      // chunk visible
    float4 ra0 = *(const float4*)&buf[qa][4*ln];
    float4 ra1 = *(const float4*)&buf[qa][256 + 4*ln];
    float4 rb0 = *(const float4*)&buf[qb][4*ln];
    float4 rb1 = *(const float4*)&buf[qb][256 + 4*ln];
    const int o = c*8;
    su0[o+0]=ra0.x; su0[o+1]=ra0.y; su0[o+2]=ra0.z; su0[o+3]=ra0.w;
    su0[o+4]=ra1.x; su0[o+5]=ra1.y; su0[o+6]=ra1.z; su0[o+7]=ra1.w;
    su1[o+0]=rb0.x; su1[o+1]=rb0.y; su1[o+2]=rb0.z; su1[o+3]=rb0.w;
    su1[o+4]=rb1.x; su1[o+5]=rb1.y; su1[o+6]=rb1.z; su1[o+7]=rb1.w;
  }
  __syncthreads();   // score buf dead; region reused for cand then P halves
  // su index i (chunk c=i>>3, m=i&7) -> key:
  //   key = (ln>>4)*256 + ((m&4)<<8) + c*64 + (ln&15)*4 + (m&3)
  //   (m&4) selects key-half: i = c*8 + hp*4 + jj covers half hp.

  // ----- level-1: bisect top 12 bits (row0 VALU+shfl, row1 ballot/SALU) -----
  unsigned p0 = 0, p1 = 0;
  #pragma unroll 1
  for (int bit = 31; bit >= 20; --bit){
    const float c0f = umt(p0 | (1u << bit));
    const float c1f = umt(p1 | (1u << bit));
    int v0 = 0, n1 = 0;
    #pragma unroll
    for (int i = 0; i < 32; i++){
      v0 += (su0[i] >= c0f) ? 1 : 0;                      // VALU per-lane
      n1 += (int)__popcll(__ballot(su1[i] >= c1f));       // SALU count
    }
    #pragma unroll
    for (int m=1;m<64;m<<=1) v0 += __shfl_xor(v0,m,64);   // DS reduce (row0)
    p0 |= (v0 >= 206) ? (1u << bit) : 0u;
    if (n1 >= 206) p1 |= (1u << bit);
  }

  const int b = bh >> 2, h = bh & 3;

  // ----- both rows interleaved: scan, bisect, v205 -----
  // cand buffers live in the dead score-buf region [0,8192), wave-private.
  const float pf0  = umt(p0),             pf1  = umt(p1);
  const float hif0 = umt(p0 + 0x100000u), hif1 = umt(p1 + 0x100000u);
  float* cand0 = (float*)(smem + (size_t)w*1024);
  float* cand1 = (float*)(smem + (size_t)w*1024 + 512);

  int above0 = 0, nc0 = 0, above1 = 0, nc1 = 0;
  float mx0 = -3.0e38f, mx1 = -3.0e38f, mnab0 = 3.0e38f, mnab1 = 3.0e38f;
  #pragma unroll
  for (int i = 0; i < 32; i++){
    const float u0 = su0[i], u1 = su1[i];
    mx0 = fmaxf(mx0, u0);
    mx1 = fmaxf(mx1, u1);
    const bool ab0 = (u0 >= hif0), ab1 = (u1 >= hif1);
    above0 += ab0 ? 1 : 0;                 // VALU per-lane
    above1 += ab1 ? 1 : 0;
    if (ab0) mnab0 = fminf(mnab0, u0);
    if (ab1) mnab1 = fminf(mnab1, u1);
    const bool cd0 = (u0 >= pf0) && !ab0, cd1 = (u1 >= pf1) && !ab1;
    const unsigned long long bal0 = __ballot(cd0);
    if (cd0){
      const int pos = nc0 + mbcnt64(bal0);
      if (pos < CAP) cand0[pos] = u0;
    }
    nc0 += (int)__popcll(bal0);
    const unsigned long long bal1 = __ballot(cd1);
    if (cd1){
      const int pos = nc1 + mbcnt64(bal1);
      if (pos < CAP) cand1[pos] = u1;
    }
    nc1 += (int)__popcll(bal1);
  }
  int ab01 = above0 | (above1 << 16);      // packed cross-lane reduce
  #pragma unroll
  for (int m=1;m<64;m<<=1){
    ab01  += __shfl_xor(ab01, m,64);
    mx0   = fmaxf(mx0,   __shfl_xor(mx0,  m,64));
    mx1   = fmaxf(mx1,   __shfl_xor(mx1,  m,64));
    mnab0 = fminf(mnab0, __shfl_xor(mnab0,m,64));
    mnab1 = fminf(mnab1, __shfl_xor(mnab1,m,64));
  }
  above0 = ab01 & 0xffff;
  above1 = ab01 >> 16;

  float v206_0, v205_0, v206_1, v205_1;
  if (__builtin_expect(nc0 <= CAP && nc1 <= CAP, 1)){
    const int j0 = 206 - above0, j1 = 206 - above1;
    const float cv00 = (ln      < nc0) ? cand0[ln]      : -3.0e38f;
    const float cv01 = (ln + 64 < nc0) ? cand0[ln + 64] : -3.0e38f;
    const float cv10 = (ln      < nc1) ? cand1[ln]      : -3.0e38f;
    const float cv11 = (ln + 64 < nc1) ? cand1[ln + 64] : -3.0e38f;
    unsigned v0 = p0, v1 = p1;
    #pragma unroll 1
    for (int bit = 19; bit >= 0; --bit){
      const float cf0 = umt(v0 | (1u << bit));
      const float cf1 = umt(v1 | (1u << bit));
      const int n0 = (int)__popcll(__ballot(cv00 >= cf0))
                   + (int)__popcll(__ballot(cv01 >= cf0));
      const int n1 = (int)__popcll(__ballot(cv10 >= cf1))
                   + (int)__popcll(__ballot(cv11 >= cf1));
      if (n0 >= j0) v0 |= (1u << bit);
      if (n1 >= j1) v1 |= (1u << bit);
    }
    v206_0 = umt(v0);
    v206_1 = umt(v1);
    const int cgtc0 = (int)__popcll(__ballot(cv00 > v206_0))
                    + (int)__popcll(__ballot(cv01 > v206_0));
    const int cgtc1 = (int)__popcll(__ballot(cv10 > v206_1))
                    + (int)__popcll(__ballot(cv11 > v206_1));
    float mnc0 = 3.0e38f, mnc1 = 3.0e38f;
    if (cv00 > v206_0) mnc0 = fminf(mnc0, cv00);
    if (cv01 > v206_0) mnc0 = fminf(mnc0, cv01);
    if (cv10 > v206_1) mnc1 = fminf(mnc1, cv10);
    if (cv11 > v206_1) mnc1 = fminf(mnc1, cv11);
    #pragma unroll
    for (int m=1;m<64;m<<=1){
      mnc0 = fminf(mnc0, __shfl_xor(mnc0,m,64));
      mnc1 = fminf(mnc1, __shfl_xor(mnc1,m,64));
    }
    const int cgt0 = above0 + cgtc0, cgt1 = above1 + cgtc1;
    v205_0 = (cgt0 == 205) ? ((cgtc0 > 0) ? mnc0 : mnab0) : v206_0;
    v205_1 = (cgt1 == 205) ? ((cgtc1 > 0) ? mnc1 : mnab1) : v206_1;
  } else {
    FULLSEL(su0, p0, v206_0, v205_0);
    FULLSEL(su1, p1, v206_1, v205_1);
  }

  const float thr0 = (float)((double)v206_0 + 0.3*((double)v205_0 - (double)v206_0));
  const float thr1 = (float)((double)v206_1 + 0.3*((double)v205_1 - (double)v206_1));

  __syncthreads();   // all cand reads done; [0,32768) free for P halves

  // ----- probs + PV, two 1024-key halves sharing one 32KB LDS region -----
  float zl0 = 0.f, zl1 = 0.f;
  char* rba = smem + (size_t)qa*2048 + ((size_t)(ln >> 4) << 9)
            + (size_t)((((ln & 15) << 3)) ^ ((qa & 7) << 4));
  char* rbb = smem + (size_t)qb*2048 + ((size_t)(ln >> 4) << 9)
            + (size_t)((((ln & 15) << 3)) ^ ((qb & 7) << 4));

  // PV wave split: ct = w&3 -> dim tile, khq = w>>2 -> 512-key quarter per half
  const int ct = w & 3, khq = w >> 2;
  const int arow = ln & 15;
  const int sw = (arow & 7) << 4;       // involution on byte bits 4-6
  const char* prow = smem + (size_t)arow*2048;
  const int klog0 = (khq << 10) + ((ln >> 4) << 4);
  floatx4 acch = {0.f,0.f,0.f,0.f};
  floatx4 accl = {0.f,0.f,0.f,0.f};

  #pragma unroll
  for (int hp = 0; hp < 2; hp++){
    // dense probs for key-half hp: p = s>=thr ? exp(s-mx) : 0 -> f16
    #pragma unroll
    for (int c = 0; c < 4; c++){
      half4v pk0, pk1;
      #pragma unroll
      for (int jj = 0; jj < 4; jj++){
        const int i = c*8 + hp*4 + jj;
        const float s0 = su0[i], s1 = su1[i];
        const float pr0 = (s0 >= thr0) ? __expf(s0 - mx0) : 0.f;
        const float pr1 = (s1 >= thr1) ? __expf(s1 - mx1) : 0.f;
        const _Float16 ph0 = (_Float16)pr0;
        const _Float16 ph1 = (_Float16)pr1;
        zl0 += (float)ph0;                // Z from f16-rounded p for consistency
        zl1 += (float)ph1;
        pk0[jj] = ph0;
        pk1[jj] = ph1;
      }
      *(half4v*)(rba + c*128) = pk0;
      *(half4v*)(rbb + c*128) = pk1;
    }
    if (hp == 1){
      #pragma unroll
      for (int m=1;m<64;m<<=1){
        zl0 += __shfl_xor(zl0,m,64);
        zl1 += __shfl_xor(zl1,m,64);
      }
      if (ln == 0){ zbuf[qa] = 1.0f / zl0; zbuf[qb] = 1.0f / zl1; }
    }
    __syncthreads();   // P half hp (+zbuf at hp==1) visible

    const _Float16* vhp_ = vth + ((size_t)bh*64 + ct*16 + arow)*2048
                         + (hp << 10) + (khq << 9) + ((ln >> 4) << 3);
    const _Float16* vlp_ = vtl + ((size_t)bh*64 + ct*16 + arow)*2048
                         + (hp << 10) + (khq << 9) + ((ln >> 4) << 3);
    #pragma unroll 4
    for (int kk = 0; kk < 16; kk++){
      const half8 a   = *(const half8*)(prow + ((klog0 + kk*64) ^ sw));
      const half8 vh8 = *(const half8*)(vhp_ + kk*32);
      const half8 vl8 = *(const half8*)(vlp_ + kk*32);
      acch = MFMAH(a, vh8, acch);
      accl = MFMAH(a, vl8, accl);
    }
    if (hp == 0) __syncthreads();   // P half0 reads done before overwrite
  }
  floatx4 acc = acch + accl;

  // distill params for khq==0 waves (loads overlap the obuf barrier)
  float gt = 0.f, bda = 0.f;
  float wdv[16];
  if (khq == 1){
    const int r0 = (ln >> 4) * 4;
    #pragma unroll
    for (int i = 0; i < 4; i++) obuf[r0+i][ct*16 + arow] = acc[i];
  } else {
    gt  = gate_ws[(size_t)b*256 + h*64 + ct*16 + arow];
    bda = bd[arow];
    #pragma unroll
    for (int m4 = 0; m4 < 4; m4++){
      const float4 t4 = *(const float4*)&Wd[arow*16 + m4*4];
      wdv[m4*4+0]=t4.x; wdv[m4*4+1]=t4.y; wdv[m4*4+2]=t4.z; wdv[m4*4+3]=t4.w;
    }
  }
  __syncthreads();
  if (khq == 0){
    const int r0 = (ln >> 4) * 4;
    const int gb = ln & 48;              // 16-lane group base = distill group
    #pragma unroll
    for (int i = 0; i < 4; i++){
      const int r = r0 + i;
      const float o = (acc[i] + obuf[r][ct*16 + arow]) * zbuf[r];
      float d = bda;
      #pragma unroll
      for (int m = 0; m < 16; m++)
        d = fmaf(__shfl(o, gb + m, 64), wdv[m], d);
      const float mixed = gt*d + (1.0f - gt)*o;
      mix_ws[(size_t)(b*2048 + q0 + r)*256 + h*64 + ct*16 + arow] = mixed;
    }
  }
}

// ---------- K4: out = mixed @ Wo^T + bo, LDS-staged bf16 hi/lo MFMA ----------
__global__ __launch_bounds__(256) void out_gemm(
    const float* __restrict__ A, const float* __restrict__ Wo,
    const float* __restrict__ bo, float* __restrict__ out){
  __shared__ short Ah[64][40], Al[64][40];
  __shared__ short Bh[64][40], Bl[64][40];
  const int m0 = blockIdx.x * 64;
  const int n0 = blockIdx.y * 64;
  const int tid = threadIdx.x;
  const int lr = tid >> 2, lc = tid & 3;
  const int w = tid >> 6, ln = tid & 63;
  const int lm = ln & 15, lk = (ln >> 4) * 8;

  floatx4 acc[4];
  #pragma unroll
  for (int tl=0;tl<4;tl++) acc[tl] = (floatx4){0.f,0.f,0.f,0.f};

  for (int k0 = 0; k0 < 256; k0 += 32){
    const float4 a0 = *(const float4*)&A [(size_t)(m0+lr)*256 + k0 + lc*8];
    const float4 a1 = *(const float4*)&A [(size_t)(m0+lr)*256 + k0 + lc*8 + 4];
    const float4 b0 = *(const float4*)&Wo[(size_t)(n0+lr)*256 + k0 + lc*8];
    const float4 b1 = *(const float4*)&Wo[(size_t)(n0+lr)*256 + k0 + lc*8 + 4];
    __syncthreads();
    cvt8(&Ah[lr][lc*8], &Al[lr][lc*8], a0, a1);
    cvt8(&Bh[lr][lc*8], &Bl[lr][lc*8], b0, b1);
    __syncthreads();
    const short8 ah8 = *(const short8*)&Ah[w*16+lm][lk];
    const short8 al8 = *(const short8*)&Al[w*16+lm][lk];
    #pragma unroll
    for (int tl = 0; tl < 4; tl++){
      const short8 bh8 = *(const short8*)&Bh[tl*16+lm][lk];
      const short8 bl8 = *(const short8*)&Bl[tl*16+lm][lk];
      acc[tl] = MFMA16(ah8, bh8, acc[tl]);
      acc[tl] = MFMA16(al8, bh8, acc[tl]);
      acc[tl] = MFMA16(ah8, bl8, acc[tl]);
      acc[tl] = MFMA16(al8, bl8, acc[tl]);
    }
  }

  #pragma unroll
  for (int tl = 0; tl < 4; tl++){
    const int f = n0 + tl*16 + lm;
    const float bf = bo[f];
    #pragma unroll
    for (int i=0;i<4;i++){
      const int m = m0 + w*16 + (ln >> 4)*4 + i;
      out[(size_t)m*256 + f] = acc[tl][i] + bf;
    }
  }
}

// ---------- launch ----------
extern "C" void kernel_launch(void* const* d_in, const int* in_sizes, int n_in,
                              void* d_out, int out_size, void* d_ws, size_t ws_size,
                              hipStream_t stream) {
  const float* x   = (const float*)d_in[0];
  const float* Wq  = (const float*)d_in[1];  const float* bq  = (const float*)d_in[2];
  const float* Wk  = (const float*)d_in[3];  const float* bk  = (const float*)d_in[4];
  const float* Wv  = (const float*)d_in[5];  const float* bv  = (const float*)d_in[6];
  const float* Wd  = (const float*)d_in[7];  const float* bd  = (const float*)d_in[8];
  const float* Wg  = (const float*)d_in[9];  const float* bg  = (const float*)d_in[10];
  const float* Wgp = (const float*)d_in[11]; const float* bgp = (const float*)d_in[12];
  const float* Wo  = (const float*)d_in[13]; const float* bo  = (const float*)d_in[14];

  char* base = (char*)d_ws;
  float* mix_ws = (float*)(base);                       // 8 MB
  __hip_bfloat16* qh = (__hip_bfloat16*)(base + (size_t)( 8<<20));  // 4 MB
  __hip_bfloat16* ql = (__hip_bfloat16*)(base + (size_t)(12<<20));  // 4 MB
  __hip_bfloat16* kh = (__hip_bfloat16*)(base + (size_t)(16<<20));  // 4 MB
  __hip_bfloat16* kl = (__hip_bfloat16*)(base + (size_t)(20<<20));  // 4 MB
  _Float16* vth = (_Float16*)(base + (size_t)(24<<20));             // 4 MB (V^T hi)
  _Float16* vtl = (_Float16*)(base + (size_t)(28<<20));             // 4 MB (V^T lo)
  float* xpart  = (float*)(base + (size_t)(32<<20));    // 512 KB
  float* gate_ws= (float*)(base + (size_t)(33<<20));

  xpart_kernel<<<dim3(128,4), 256, 0, stream>>>(x, xpart);
  gate_kernel<<<4, 256, 0, stream>>>(xpart, Wg, bg, Wgp, bgp, gate_ws);
  qkv_gemm<<<dim3(128,12), 256, 0, stream>>>(x, Wq,bq, Wk,bk, Wv,bv,
                                             qh, ql, kh, kl, vth, vtl);
  attn_kernel<<<dim3(128,16), 512, 0, stream>>>(qh, ql, kh, kl, vth, vtl,
                                                Wd, bd, gate_ws, mix_ws);
  out_gemm<<<dim3(128,4), 256, 0, stream>>>(mix_ws, Wo, bo, (float*)d_out);
}

// Round 12
// 397.005 us; speedup vs baseline: 1.0471x; 1.0222x over previous
//
#include <hip/hip_runtime.h>
#include <hip/hip_bf16.h>
#include <math.h>

// B=4, S=2048, D=256, H=4, HD=64; keep top-10% per score row.
// thr = v206 + 0.3*(v205 - v206)  (v_k = k-th largest), exact via bit-bisection.
//
// Round-11 finding: occupancy is capped by the unified VGPR+AGPR file
// (su[64] scores/wave => ~128 regs/wave => 16 waves/CU), NOT by LDS. So LDS
// up to 80KB/block is free at the forced 2 blocks/CU:
//  - attn: restore ping-pong score handoff (1 barrier/chunk); keep halved-P PV;
//    cand in dead buf1 region (no extra barrier; P-half0 is in buf0's region).
//    LDS 70336B, 9 barriers/block (was 11).
//  - GEMMs: operands pre-converted to bf16 hi/lo (x-split fused into xpart,
//    wconv for weights, attn epilogue emits mixh/mixl) -> staged short8 direct,
//    no per-iter cvt, half the staged global bytes. All pieces round-7/8-proven.

#define CAP 128

typedef __attribute__((ext_vector_type(8))) short short8;
typedef __attribute__((ext_vector_type(4))) float floatx4;
typedef _Float16 half8 __attribute__((ext_vector_type(8)));
typedef _Float16 half4v __attribute__((ext_vector_type(4)));
#define MFMA16(a,b,c) __builtin_amdgcn_mfma_f32_16x16x32_bf16(a,b,c,0,0,0)
#define MFMAH(a,b,c)  __builtin_amdgcn_mfma_f32_16x16x32_f16(a,b,c,0,0,0)

// ---------- helpers ----------
__device__ __forceinline__ float umt(unsigned u){
  return __uint_as_float((u & 0x80000000u) ? (u & 0x7fffffffu) : ~u);
}
__device__ __forceinline__ float wmin_f(float v){
  #pragma unroll
  for (int m=1;m<64;m<<=1) v = fminf(v, __shfl_xor(v,m,64));
  return v;
}
__device__ __forceinline__ int mbcnt64(unsigned long long m){
  return (int)__builtin_amdgcn_mbcnt_hi((unsigned)(m>>32),
         __builtin_amdgcn_mbcnt_lo((unsigned)(m & 0xffffffffull), 0u));
}
__device__ __forceinline__ short8 ldb8(const __hip_bfloat16* p){
  return *(const short8*)p;
}

// full-register 20-bit bisection + v205 recovery (exact, used as rare fallback)
#define FULLSEL(SU, PSTART, V206, V205)                                        \
  {                                                                            \
    unsigned v = (PSTART);                                                     \
    _Pragma("unroll 1")                                                        \
    for (int bit = 19; bit >= 0; --bit){                                       \
      const float cf = umt(v | (1u << bit));                                   \
      int n = 0;                                                               \
      _Pragma("unroll")                                                        \
      for (int i = 0; i < 32; i++) n += (int)__popcll(__ballot(SU[i] >= cf));  \
      if (n >= 206) v |= (1u << bit);                                          \
    }                                                                          \
    V206 = umt(v);                                                             \
    int cgt = 0; float mn = 3.0e38f;                                           \
    _Pragma("unroll")                                                          \
    for (int i = 0; i < 32; i++){                                              \
      const float u = SU[i];                                                   \
      const bool gt = (u > V206);                                              \
      cgt += (int)__popcll(__ballot(gt));                                      \
      mn = (gt && u < mn) ? u : mn;                                            \
    }                                                                          \
    mn = wmin_f(mn);                                                           \
    V205 = (cgt == 205) ? mn : V206;                                           \
  }

// ---------- K0a: column-sum partials of x + bf16 hi/lo split ----------
__global__ void xpart_kernel(const float* __restrict__ x, float* __restrict__ xpart,
                             __hip_bfloat16* __restrict__ xh, __hip_bfloat16* __restrict__ xl){
  const int ch = blockIdx.x, b = blockIdx.y, t = threadIdx.x;   // ch in [0,128)
  const size_t base = ((size_t)b*2048 + (size_t)ch*16)*256 + t;
  float s = 0.f;
  #pragma unroll
  for (int i=0;i<16;i++){
    const float v = x[base + (size_t)i*256];
    s += v;
    const __hip_bfloat16 h = __float2bfloat16(v);
    xh[base + (size_t)i*256] = h;
    xl[base + (size_t)i*256] = __float2bfloat16(v - __bfloat162float(h));
  }
  xpart[(size_t)(b*128+ch)*256 + t] = s;
}

// ---------- K0c: weight bf16 hi/lo split (Wq,Wk,Wv,Wo -> [mat][256][256]) ----------
__global__ void wconv_kernel(const float* __restrict__ Wq, const float* __restrict__ Wk,
                             const float* __restrict__ Wv, const float* __restrict__ Wo,
                             __hip_bfloat16* __restrict__ wh, __hip_bfloat16* __restrict__ wl){
  const int mat = blockIdx.x >> 6;
  const float* W = (mat==0) ? Wq : (mat==1) ? Wk : (mat==2) ? Wv : Wo;
  const int off = (blockIdx.x & 63)*1024 + threadIdx.x*4;
  const float4 v = *(const float4*)&W[off];
  const float vv[4] = {v.x, v.y, v.z, v.w};
  short hs[4], ls[4];
  #pragma unroll
  for (int i=0;i<4;i++){
    const __hip_bfloat16 h = __float2bfloat16(vv[i]);
    const __hip_bfloat16 l = __float2bfloat16(vv[i] - __bfloat162float(h));
    hs[i] = *(const short*)&h; ls[i] = *(const short*)&l;
  }
  const size_t o = (size_t)mat*65536 + off;
  *(short4*)((short*)wh + o) = make_short4(hs[0],hs[1],hs[2],hs[3]);
  *(short4*)((short*)wl + o) = make_short4(ls[0],ls[1],ls[2],ls[3]);
}

// ---------- K0b: gate[b][256], one block per batch, parallel matvec ----------
__global__ void gate_kernel(const float* __restrict__ xpart,
                            const float* __restrict__ Wg, const float* __restrict__ bg,
                            const float* __restrict__ Wgp,const float* __restrict__ bgp,
                            float* __restrict__ gate_ws){
  __shared__ float xm[256];
  __shared__ float part[16][17];
  __shared__ float g16[16];
  const int t = threadIdx.x;
  const int b = blockIdx.x;
  float s = 0.f;
  for (int ch=0; ch<128; ch++) s += xpart[(size_t)(b*128+ch)*256 + t];
  xm[t] = s * (1.0f/2048.0f);
  __syncthreads();
  {
    const int j = t >> 4, dg = t & 15;
    float p = 0.f;
    #pragma unroll
    for (int d=0; d<16; d++) p = fmaf(xm[dg*16+d], Wg[j*256 + dg*16 + d], p);
    part[j][dg] = p;
  }
  __syncthreads();
  if (t < 16){
    float z = bg[t];
    #pragma unroll
    for (int g=0; g<16; g++) z += part[t][g];
    g16[t] = 1.0f/(1.0f + __expf(-z));
  }
  __syncthreads();
  float z2 = bgp[t];
  #pragma unroll
  for (int j=0;j<16;j++) z2 = fmaf(g16[j], Wgp[t*16+j], z2);
  gate_ws[b*256 + t] = z2;
}

// ---------- K1: fused QKV projection, LDS-staged bf16 hi/lo MFMA (pre-converted) ----------
__global__ __launch_bounds__(256) void qkv_gemm(
    const __hip_bfloat16* __restrict__ xh, const __hip_bfloat16* __restrict__ xl,
    const __hip_bfloat16* __restrict__ wh, const __hip_bfloat16* __restrict__ wl,
    const float* __restrict__ bq, const float* __restrict__ bk, const float* __restrict__ bv,
    __hip_bfloat16* __restrict__ qh, __hip_bfloat16* __restrict__ ql,
    __hip_bfloat16* __restrict__ kh, __hip_bfloat16* __restrict__ kl,
    _Float16* __restrict__ vth, _Float16* __restrict__ vtl){
  __shared__ short Ah[64][40], Al[64][40];   // 80B rows: 16B-aligned, bank stride 20
  __shared__ short Bh[64][40], Bl[64][40];
  const int m0 = blockIdx.x * 64;
  const int n0g = blockIdx.y * 64;          // global col tile in [0,768)
  const int sect = n0g >> 8;                // 0:Q 1:K 2:V
  const int nl0 = n0g & 255;
  const __hip_bfloat16* Wh = wh + (size_t)sect*65536;
  const __hip_bfloat16* Wl = wl + (size_t)sect*65536;
  const float* bias = (sect==0) ? bq : ((sect==1) ? bk : bv);
  const int tid = threadIdx.x;
  const int lr = tid >> 2, lc = tid & 3;
  const int w = tid >> 6, ln = tid & 63;
  const int lm = ln & 15, lk = (ln >> 4) * 8;

  floatx4 acc[4];
  #pragma unroll
  for (int tl=0;tl<4;tl++) acc[tl] = (floatx4){0.f,0.f,0.f,0.f};

  for (int k0 = 0; k0 < 256; k0 += 32){
    const short8 a_h = ldb8(xh + (size_t)(m0 +lr)*256 + k0 + lc*8);
    const short8 a_l = ldb8(xl + (size_t)(m0 +lr)*256 + k0 + lc*8);
    const short8 b_h = ldb8(Wh + (size_t)(nl0+lr)*256 + k0 + lc*8);
    const short8 b_l = ldb8(Wl + (size_t)(nl0+lr)*256 + k0 + lc*8);
    __syncthreads();                       // previous iter frag reads done
    *(short8*)&Ah[lr][lc*8] = a_h;
    *(short8*)&Al[lr][lc*8] = a_l;
    *(short8*)&Bh[lr][lc*8] = b_h;
    *(short8*)&Bl[lr][lc*8] = b_l;
    __syncthreads();                       // staged tile visible
    const short8 ah8 = *(const short8*)&Ah[w*16+lm][lk];
    const short8 al8 = *(const short8*)&Al[w*16+lm][lk];
    #pragma unroll
    for (int tl = 0; tl < 4; tl++){
      const short8 bh8 = *(const short8*)&Bh[tl*16+lm][lk];
      const short8 bl8 = *(const short8*)&Bl[tl*16+lm][lk];
      acc[tl] = MFMA16(ah8, bh8, acc[tl]);
      acc[tl] = MFMA16(al8, bh8, acc[tl]);
      acc[tl] = MFMA16(ah8, bl8, acc[tl]);
      acc[tl] = MFMA16(al8, bl8, acc[tl]);
    }
  }

  // D layout: row = (ln>>4)*4 + i (M), col = ln&15 (N)
  #pragma unroll
  for (int tl = 0; tl < 4; tl++){
    const int f = nl0 + tl*16 + lm;        // feature in [0,256)
    const int hh = f >> 6, hd = f & 63;
    const float bf = bias[f];
    if (sect == 2){
      const int mB = m0 + w*16 + (ln >> 4)*4;  // 4 consecutive s values
      const int bidx = mB >> 11, s0 = mB & 2047;
      half4v hv, lv;
      #pragma unroll
      for (int i=0;i<4;i++){
        const float val = acc[tl][i] + bf;
        const _Float16 hx = (_Float16)val;
        hv[i] = hx;
        lv[i] = (_Float16)(val - (float)hx);
      }
      const size_t row = (size_t)((bidx*4+hh)*64 + hd);
      *(half4v*)(vth + row*2048 + s0) = hv;
      *(half4v*)(vtl + row*2048 + s0) = lv;
    } else {
      #pragma unroll
      for (int i=0;i<4;i++){
        const int m = m0 + w*16 + (ln >> 4)*4 + i;
        const int bidx = m >> 11, s = m & 2047;
        const float val = acc[tl][i] + bf;
        const size_t idx = (size_t)((bidx*4+hh)*2048 + s)*64 + hd;
        const __hip_bfloat16 hi = __float2bfloat16(val);
        const float lo = val - __bfloat162float(hi);
        if (sect == 0){ qh[idx] = hi; ql[idx] = __float2bfloat16(lo); }
        else          { kh[idx] = hi; kl[idx] = __float2bfloat16(lo); }
      }
    }
  }
}

// ---------- K2: sparse attention + fused distill/gate mix ----------
// smem map (70336 B, 2 blocks/CU — reg-capped anyway):
//  [0, 33024)      buf0: score chunks 0,2   | later: P-half [16][1024] f16 (32KB)
//  [33024, 66048)  buf1: score chunks 1,3   | later: cand scratch (16x512B)
//  [66048, 70272)  obuf[16][66] cross-quarter PV reduce
//  [70272, 70336)  zbuf[16]
__global__ __launch_bounds__(512, 4) void attn_kernel(
    const __hip_bfloat16* __restrict__ qh, const __hip_bfloat16* __restrict__ ql,
    const __hip_bfloat16* __restrict__ kh, const __hip_bfloat16* __restrict__ kl,
    const _Float16* __restrict__ vth, const _Float16* __restrict__ vtl,
    const float* __restrict__ Wd, const float* __restrict__ bd,
    const float* __restrict__ gate_ws,
    __hip_bfloat16* __restrict__ mixh, __hip_bfloat16* __restrict__ mixl){
  __shared__ __align__(16) char smem[70336];
  float (*buf0)[516] = (float (*)[516])smem;
  float (*buf1)[516] = (float (*)[516])(smem + 33024);
  float (*obuf)[66] = (float (*)[66])(smem + 66048);
  float* zbuf = (float*)(smem + 70272);

  const int bh = blockIdx.y;
  const int q0 = blockIdx.x * 16;
  const int tid = threadIdx.x;
  const int w = tid >> 6, ln = tid & 63;
  const int lm = ln & 15;
  const int lk = (ln >> 4) * 8;
  const int qa = 2*w, qb = 2*w + 1;

  const __hip_bfloat16* Qh = qh + ((size_t)bh*2048 + q0)*64;
  const __hip_bfloat16* Ql = ql + ((size_t)bh*2048 + q0)*64;
  const __hip_bfloat16* Kh = kh + ((size_t)bh*2048 + w*256)*64;
  const __hip_bfloat16* Kl = kl + ((size_t)bh*2048 + w*256)*64;

  float su0[32], su1[32];

  // Q fragments are chunk-invariant: hoist.
  const short8 ah0 = ldb8(Qh + lm*64 + lk);
  const short8 ah1 = ldb8(Qh + lm*64 + 32 + lk);
  const short8 al0 = ldb8(Ql + lm*64 + lk);
  const short8 al1 = ldb8(Ql + lm*64 + 32 + lk);

  // ----- rounds: MFMA 4 tiles -> ping-pong LDS handoff (1 barrier/chunk) -----
  #pragma unroll
  for (int c = 0; c < 4; c++){
    float (*bufc)[516] = (c & 1) ? buf1 : buf0;
    floatx4 acc[4];
    #pragma unroll
    for (int tl = 0; tl < 4; tl++){
      const int krow = c*64 + tl*16 + lm;
      short8 bh0 = ldb8(Kh + krow*64 + lk);
      short8 bh1 = ldb8(Kh + krow*64 + 32 + lk);
      short8 bl0 = ldb8(Kl + krow*64 + lk);
      short8 bl1 = ldb8(Kl + krow*64 + 32 + lk);
      floatx4 a = {0.f,0.f,0.f,0.f};
      a = MFMA16(ah0, bh0, a);
      a = MFMA16(ah1, bh1, a);
      a = MFMA16(al0, bh0, a);
      a = MFMA16(al1, bh1, a);
      a = MFMA16(ah0, bl0, a);
      a = MFMA16(ah1, bl1, a);
      a = MFMA16(al0, bl0, a);
      a = MFMA16(al1, bl1, a);
      acc[tl] = a;
    }
    const int wr = (ln >> 4) * 4;         // C-layout: row=(lane>>4)*4+reg, col=lane&15
    #pragma unroll
    for (int tl = 0; tl < 4; tl++){
      const int col = w*64 + tl*16 + lm;
      bufc[wr+0][col] = acc[tl].x * 0.125f;
      bufc[wr+1][col] = acc[tl].y * 0.125f;
      bufc[wr+2][col] = acc[tl].z * 0.125f;
      bufc[wr+3][col] = acc[tl].w * 0.125f;
    }
    __syncthreads();                      // chunk c visible; c-1 readers all done
    float4 ra0 = *(const float4*)&bufc[qa][4*ln];
    float4 ra1 = *(const float4*)&bufc[qa][256 + 4*ln];
    float4 rb0 = *(const float4*)&bufc[qb][4*ln];
    float4 rb1 = *(const float4*)&bufc[qb][256 + 4*ln];
    const int o = c*8;
    su0[o+0]=ra0.x; su0[o+1]=ra0.y; su0[o+2]=ra0.z; su0[o+3]=ra0.w;
    su0[o+4]=ra1.x; su0[o+5]=ra1.y; su0[o+6]=ra1.z; su0[o+7]=ra1.w;
    su1[o+0]=rb0.x; su1[o+1]=rb0.y; su1[o+2]=rb0.z; su1[o+3]=rb0.w;
    su1[o+4]=rb1.x; su1[o+5]=rb1.y; su1[o+6]=rb1.z; su1[o+7]=rb1.w;
  }
  __syncthreads();   // chunk-3 reads (buf1) done; buf1 region free for cand
  // su index i (chunk c=i>>3, m=i&7) -> key:
  //   key = (ln>>4)*256 + ((m&4)<<8) + c*64 + (ln&15)*4 + (m&3)
  //   (m&4) selects key-half: i = c*8 + hp*4 + jj covers half hp.

  // ----- level-1: bisect top 12 bits (row0 VALU+shfl, row1 ballot/SALU) -----
  unsigned p0 = 0, p1 = 0;
  #pragma unroll 1
  for (int bit = 31; bit >= 20; --bit){
    const float c0f = umt(p0 | (1u << bit));
    const float c1f = umt(p1 | (1u << bit));
    int v0 = 0, n1 = 0;
    #pragma unroll
    for (int i = 0; i < 32; i++){
      v0 += (su0[i] >= c0f) ? 1 : 0;                      // VALU per-lane
      n1 += (int)__popcll(__ballot(su1[i] >= c1f));       // SALU count
    }
    #pragma unroll
    for (int m=1;m<64;m<<=1) v0 += __shfl_xor(v0,m,64);   // DS reduce (row0)
    p0 |= (v0 >= 206) ? (1u << bit) : 0u;
    if (n1 >= 206) p1 |= (1u << bit);
  }

  const int b = bh >> 2, h = bh & 3;

  // ----- both rows interleaved: scan, bisect, v205 (cand in dead buf1) -----
  const float pf0  = umt(p0),             pf1  = umt(p1);
  const float hif0 = umt(p0 + 0x100000u), hif1 = umt(p1 + 0x100000u);
  float* cand0 = (float*)(smem + 33024 + (size_t)w*1024);
  float* cand1 = (float*)(smem + 33024 + (size_t)w*1024 + 512);

  int above0 = 0, nc0 = 0, above1 = 0, nc1 = 0;
  float mx0 = -3.0e38f, mx1 = -3.0e38f, mnab0 = 3.0e38f, mnab1 = 3.0e38f;
  #pragma unroll
  for (int i = 0; i < 32; i++){
    const float u0 = su0[i], u1 = su1[i];
    mx0 = fmaxf(mx0, u0);
    mx1 = fmaxf(mx1, u1);
    const bool ab0 = (u0 >= hif0), ab1 = (u1 >= hif1);
    above0 += ab0 ? 1 : 0;                 // VALU per-lane
    above1 += ab1 ? 1 : 0;
    if (ab0) mnab0 = fminf(mnab0, u0);
    if (ab1) mnab1 = fminf(mnab1, u1);
    const bool cd0 = (u0 >= pf0) && !ab0, cd1 = (u1 >= pf1) && !ab1;
    const unsigned long long bal0 = __ballot(cd0);
    if (cd0){
      const int pos = nc0 + mbcnt64(bal0);
      if (pos < CAP) cand0[pos] = u0;
    }
    nc0 += (int)__popcll(bal0);
    const unsigned long long bal1 = __ballot(cd1);
    if (cd1){
      const int pos = nc1 + mbcnt64(bal1);
      if (pos < CAP) cand1[pos] = u1;
    }
    nc1 += (int)__popcll(bal1);
  }
  int ab01 = above0 | (above1 << 16);      // packed cross-lane reduce
  #pragma unroll
  for (int m=1;m<64;m<<=1){
    ab01  += __shfl_xor(ab01, m,64);
    mx0   = fmaxf(mx0,   __shfl_xor(mx0,  m,64));
    mx1   = fmaxf(mx1,   __shfl_xor(mx1,  m,64));
    mnab0 = fminf(mnab0, __shfl_xor(mnab0,m,64));
    mnab1 = fminf(mnab1, __shfl_xor(mnab1,m,64));
  }
  above0 = ab01 & 0xffff;
  above1 = ab01 >> 16;

  float v206_0, v205_0, v206_1, v205_1;
  if (__builtin_expect(nc0 <= CAP && nc1 <= CAP, 1)){
    const int j0 = 206 - above0, j1 = 206 - above1;
    const float cv00 = (ln      < nc0) ? cand0[ln]      : -3.0e38f;
    const float cv01 = (ln + 64 < nc0) ? cand0[ln + 64] : -3.0e38f;
    const float cv10 = (ln      < nc1) ? cand1[ln]      : -3.0e38f;
    const float cv11 = (ln + 64 < nc1) ? cand1[ln + 64] : -3.0e38f;
    unsigned v0 = p0, v1 = p1;
    #pragma unroll 1
    for (int bit = 19; bit >= 0; --bit){
      const float cf0 = umt(v0 | (1u << bit));
      const float cf1 = umt(v1 | (1u << bit));
      const int n0 = (int)__popcll(__ballot(cv00 >= cf0))
                   + (int)__popcll(__ballot(cv01 >= cf0));
      const int n1 = (int)__popcll(__ballot(cv10 >= cf1))
                   + (int)__popcll(__ballot(cv11 >= cf1));
      if (n0 >= j0) v0 |= (1u << bit);
      if (n1 >= j1) v1 |= (1u << bit);
    }
    v206_0 = umt(v0);
    v206_1 = umt(v1);
    const int cgtc0 = (int)__popcll(__ballot(cv00 > v206_0))
                    + (int)__popcll(__ballot(cv01 > v206_0));
    const int cgtc1 = (int)__popcll(__ballot(cv10 > v206_1))
                    + (int)__popcll(__ballot(cv11 > v206_1));
    float mnc0 = 3.0e38f, mnc1 = 3.0e38f;
    if (cv00 > v206_0) mnc0 = fminf(mnc0, cv00);
    if (cv01 > v206_0) mnc0 = fminf(mnc0, cv01);
    if (cv10 > v206_1) mnc1 = fminf(mnc1, cv10);
    if (cv11 > v206_1) mnc1 = fminf(mnc1, cv11);
    #pragma unroll
    for (int m=1;m<64;m<<=1){
      mnc0 = fminf(mnc0, __shfl_xor(mnc0,m,64));
      mnc1 = fminf(mnc1, __shfl_xor(mnc1,m,64));
    }
    const int cgt0 = above0 + cgtc0, cgt1 = above1 + cgtc1;
    v205_0 = (cgt0 == 205) ? ((cgtc0 > 0) ? mnc0 : mnab0) : v206_0;
    v205_1 = (cgt1 == 205) ? ((cgtc1 > 0) ? mnc1 : mnab1) : v206_1;
  } else {
    FULLSEL(su0, p0, v206_0, v205_0);
    FULLSEL(su1, p1, v206_1, v205_1);
  }

  const float thr0 = (float)((double)v206_0 + 0.3*((double)v205_0 - (double)v206_0));
  const float thr1 = (float)((double)v206_1 + 0.3*((double)v205_1 - (double)v206_1));

  // ----- probs + PV, two 1024-key halves in buf0's region (no barrier needed:
  //       buf0 reads ended before the post-loop barrier; cand is in buf1) -----
  float zl0 = 0.f, zl1 = 0.f;
  char* rba = smem + (size_t)qa*2048 + ((size_t)(ln >> 4) << 9)
            + (size_t)((((ln & 15) << 3)) ^ ((qa & 7) << 4));
  char* rbb = smem + (size_t)qb*2048 + ((size_t)(ln >> 4) << 9)
            + (size_t)((((ln & 15) << 3)) ^ ((qb & 7) << 4));

  // PV wave split: ct = w&3 -> dim tile, khq = w>>2 -> 512-key quarter per half
  const int ct = w & 3, khq = w >> 2;
  const int arow = ln & 15;
  const int sw = (arow & 7) << 4;       // involution on byte bits 4-6
  const char* prow = smem + (size_t)arow*2048;
  const int klog0 = (khq << 10) + ((ln >> 4) << 4);
  floatx4 acch = {0.f,0.f,0.f,0.f};
  floatx4 accl = {0.f,0.f,0.f,0.f};

  #pragma unroll
  for (int hp = 0; hp < 2; hp++){
    // dense probs for key-half hp: p = s>=thr ? exp(s-mx) : 0 -> f16
    #pragma unroll
    for (int c = 0; c < 4; c++){
      half4v pk0, pk1;
      #pragma unroll
      for (int jj = 0; jj < 4; jj++){
        const int i = c*8 + hp*4 + jj;
        const float s0 = su0[i], s1 = su1[i];
        const float pr0 = (s0 >= thr0) ? __expf(s0 - mx0) : 0.f;
        const float pr1 = (s1 >= thr1) ? __expf(s1 - mx1) : 0.f;
        const _Float16 ph0 = (_Float16)pr0;
        const _Float16 ph1 = (_Float16)pr1;
        zl0 += (float)ph0;                // Z from f16-rounded p for consistency
        zl1 += (float)ph1;
        pk0[jj] = ph0;
        pk1[jj] = ph1;
      }
      *(half4v*)(rba + c*128) = pk0;
      *(half4v*)(rbb + c*128) = pk1;
    }
    if (hp == 1){
      #pragma unroll
      for (int m=1;m<64;m<<=1){
        zl0 += __shfl_xor(zl0,m,64);
        zl1 += __shfl_xor(zl1,m,64);
      }
      if (ln == 0){ zbuf[qa] = 1.0f / zl0; zbuf[qb] = 1.0f / zl1; }
    }
    __syncthreads();   // P half hp (+zbuf at hp==1) visible

    const _Float16* vhp_ = vth + ((size_t)bh*64 + ct*16 + arow)*2048
                         + (hp << 10) + (khq << 9) + ((ln >> 4) << 3);
    const _Float16* vlp_ = vtl + ((size_t)bh*64 + ct*16 + arow)*2048
                         + (hp << 10) + (khq << 9) + ((ln >> 4) << 3);
    #pragma unroll 4
    for (int kk = 0; kk < 16; kk++){
      const half8 a   = *(const half8*)(prow + ((klog0 + kk*64) ^ sw));
      const half8 vh8 = *(const half8*)(vhp_ + kk*32);
      const half8 vl8 = *(const half8*)(vlp_ + kk*32);
      acch = MFMAH(a, vh8, acch);
      accl = MFMAH(a, vl8, accl);
    }
    if (hp == 0) __syncthreads();   // P half0 reads done before overwrite
  }
  floatx4 acc = acch + accl;

  // distill params for khq==0 waves (loads overlap the obuf barrier)
  float gt = 0.f, bda = 0.f;
  float wdv[16];
  if (khq == 1){
    const int r0 = (ln >> 4) * 4;
    #pragma unroll
    for (int i = 0; i < 4; i++) obuf[r0+i][ct*16 + arow] = acc[i];
  } else {
    gt  = gate_ws[(size_t)b*256 + h*64 + ct*16 + arow];
    bda = bd[arow];
    #pragma unroll
    for (int m4 = 0; m4 < 4; m4++){
      const float4 t4 = *(const float4*)&Wd[arow*16 + m4*4];
      wdv[m4*4+0]=t4.x; wdv[m4*4+1]=t4.y; wdv[m4*4+2]=t4.z; wdv[m4*4+3]=t4.w;
    }
  }
  __syncthreads();
  if (khq == 0){
    const int r0 = (ln >> 4) * 4;
    const int gb = ln & 48;              // 16-lane group base = distill group
    #pragma unroll
    for (int i = 0; i < 4; i++){
      const int r = r0 + i;
      const float o = (acc[i] + obuf[r][ct*16 + arow]) * zbuf[r];
      float d = bda;
      #pragma unroll
      for (int m = 0; m < 16; m++)
        d = fmaf(__shfl(o, gb + m, 64), wdv[m], d);
      const float mixed = gt*d + (1.0f - gt)*o;
      const size_t oidx = (size_t)(b*2048 + q0 + r)*256 + h*64 + ct*16 + arow;
      const __hip_bfloat16 mhv = __float2bfloat16(mixed);
      mixh[oidx] = mhv;
      mixl[oidx] = __float2bfloat16(mixed - __bfloat162float(mhv));
    }
  }
}

// ---------- K4: out = mixed @ Wo^T + bo, LDS-staged bf16 hi/lo MFMA ----------
__global__ __launch_bounds__(256) void out_gemm(
    const __hip_bfloat16* __restrict__ mh, const __hip_bfloat16* __restrict__ ml,
    const __hip_bfloat16* __restrict__ wh, const __hip_bfloat16* __restrict__ wl,
    const float* __restrict__ bo, float* __restrict__ out){
  __shared__ short Ah[64][40], Al[64][40];
  __shared__ short Bh[64][40], Bl[64][40];
  const int m0 = blockIdx.x * 64;
  const int n0 = blockIdx.y * 64;
  const __hip_bfloat16* Wh = wh + (size_t)3*65536;   // Wo at mat slot 3
  const __hip_bfloat16* Wl = wl + (size_t)3*65536;
  const int tid = threadIdx.x;
  const int lr = tid >> 2, lc = tid & 3;
  const int w = tid >> 6, ln = tid & 63;
  const int lm = ln & 15, lk = (ln >> 4) * 8;

  floatx4 acc[4];
  #pragma unroll
  for (int tl=0;tl<4;tl++) acc[tl] = (floatx4){0.f,0.f,0.f,0.f};

  for (int k0 = 0; k0 < 256; k0 += 32){
    const short8 a_h = ldb8(mh + (size_t)(m0+lr)*256 + k0 + lc*8);
    const short8 a_l = ldb8(ml + (size_t)(m0+lr)*256 + k0 + lc*8);
    const short8 b_h = ldb8(Wh + (size_t)(n0+lr)*256 + k0 + lc*8);
    const short8 b_l = ldb8(Wl + (size_t)(n0+lr)*256 + k0 + lc*8);
    __syncthreads();
    *(short8*)&Ah[lr][lc*8] = a_h;
    *(short8*)&Al[lr][lc*8] = a_l;
    *(short8*)&Bh[lr][lc*8] = b_h;
    *(short8*)&Bl[lr][lc*8] = b_l;
    __syncthreads();
    const short8 ah8 = *(const short8*)&Ah[w*16+lm][lk];
    const short8 al8 = *(const short8*)&Al[w*16+lm][lk];
    #pragma unroll
    for (int tl = 0; tl < 4; tl++){
      const short8 bh8 = *(const short8*)&Bh[tl*16+lm][lk];
      const short8 bl8 = *(const short8*)&Bl[tl*16+lm][lk];
      acc[tl] = MFMA16(ah8, bh8, acc[tl]);
      acc[tl] = MFMA16(al8, bh8, acc[tl]);
      acc[tl] = MFMA16(ah8, bl8, acc[tl]);
      acc[tl] = MFMA16(al8, bl8, acc[tl]);
    }
  }

  #pragma unroll
  for (int tl = 0; tl < 4; tl++){
    const int f = n0 + tl*16 + lm;
    const float bf = bo[f];
    #pragma unroll
    for (int i=0;i<4;i++){
      const int m = m0 + w*16 + (ln >> 4)*4 + i;
      out[(size_t)m*256 + f] = acc[tl][i] + bf;
    }
  }
}

// ---------- launch ----------
extern "C" void kernel_launch(void* const* d_in, const int* in_sizes, int n_in,
                              void* d_out, int out_size, void* d_ws, size_t ws_size,
                              hipStream_t stream) {
  const float* x   = (const float*)d_in[0];
  const float* Wq  = (const float*)d_in[1];  const float* bq  = (const float*)d_in[2];
  const float* Wk  = (const float*)d_in[3];  const float* bk  = (const float*)d_in[4];
  const float* Wv  = (const float*)d_in[5];  const float* bv  = (const float*)d_in[6];
  const float* Wd  = (const float*)d_in[7];  const float* bd  = (const float*)d_in[8];
  const float* Wg  = (const float*)d_in[9];  const float* bg  = (const float*)d_in[10];
  const float* Wgp = (const float*)d_in[11]; const float* bgp = (const float*)d_in[12];
  const float* Wo  = (const float*)d_in[13]; const float* bo  = (const float*)d_in[14];

  char* base = (char*)d_ws;
  __hip_bfloat16* mixh = (__hip_bfloat16*)(base);                   // 4 MB
  __hip_bfloat16* mixl = (__hip_bfloat16*)(base + (size_t)( 4<<20));// 4 MB
  __hip_bfloat16* qh = (__hip_bfloat16*)(base + (size_t)( 8<<20));  // 4 MB
  __hip_bfloat16* ql = (__hip_bfloat16*)(base + (size_t)(12<<20));  // 4 MB
  __hip_bfloat16* kh = (__hip_bfloat16*)(base + (size_t)(16<<20));  // 4 MB
  __hip_bfloat16* kl = (__hip_bfloat16*)(base + (size_t)(20<<20));  // 4 MB
  _Float16* vth = (_Float16*)(base + (size_t)(24<<20));             // 4 MB (V^T hi)
  _Float16* vtl = (_Float16*)(base + (size_t)(28<<20));             // 4 MB (V^T lo)
  __hip_bfloat16* xh = (__hip_bfloat16*)(base + (size_t)(32<<20));  // 4 MB
  __hip_bfloat16* xl = (__hip_bfloat16*)(base + (size_t)(36<<20));  // 4 MB
  __hip_bfloat16* wh = (__hip_bfloat16*)(base + (size_t)(40<<20));        // 512 KB
  __hip_bfloat16* wl = (__hip_bfloat16*)(base + (size_t)(40<<20) + (512<<10)); // 512 KB
  float* xpart  = (float*)(base + (size_t)(41<<20));    // 512 KB
  float* gate_ws= (float*)(base + (size_t)(41<<20) + (512<<10));

  xpart_kernel<<<dim3(128,4), 256, 0, stream>>>(x, xpart, xh, xl);
  wconv_kernel<<<256, 256, 0, stream>>>(Wq, Wk, Wv, Wo, wh, wl);
  gate_kernel<<<4, 256, 0, stream>>>(xpart, Wg, bg, Wgp, bgp, gate_ws);
  qkv_gemm<<<dim3(128,12), 256, 0, stream>>>(xh, xl, wh, wl, bq, bk, bv,
                                             qh, ql, kh, kl, vth, vtl);
  attn_kernel<<<dim3(128,16), 512, 0, stream>>>(qh, ql, kh, kl, vth, vtl,
                                                Wd, bd, gate_ws, mixh, mixl);
  out_gemm<<<dim3(128,4), 256, 0, stream>>>(mixh, mixl, wh, wl, bo, (float*)d_out);
}

// Round 13
// 380.808 us; speedup vs baseline: 1.0916x; 1.0425x over previous
//
#include <hip/hip_runtime.h>
#include <hip/hip_bf16.h>
#include <math.h>

// B=4, S=2048, D=256, H=4, HD=64; keep top-10% per score row.
// thr = v206 + 0.3*(v205 - v206)  (v_k = k-th largest), exact via bit-bisection.
//
// This round: replace the 12-round level-1 bisection with a 2-moment bracket.
// Per row, scores q.k_j over iid-gaussian k_j are ~exactly normal, so
// lo=mu+sd (~rank 325) / hi=mu+1.5sd (~rank 137) brackets rank 206 with wide
// margin. Candidates in [lo,hi) are compacted (CAP 256) and rank-j bisection
// over candidates is EXACT over the full 32-bit range (cf<lo: count saturates
// at nc>=j; cf>=hi: 0<j; else exact). Unconditional exactness via full-register
// 32-bit fallback when the bracket fails. Deletes ~1500 wide-ops + a 12x
// dependent shfl-reduce chain per wave from the most serialized phase.
// Rest identical to round 12 (397.0 us).

#define CAP 256

typedef __attribute__((ext_vector_type(8))) short short8;
typedef __attribute__((ext_vector_type(4))) float floatx4;
typedef _Float16 half8 __attribute__((ext_vector_type(8)));
typedef _Float16 half4v __attribute__((ext_vector_type(4)));
#define MFMA16(a,b,c) __builtin_amdgcn_mfma_f32_16x16x32_bf16(a,b,c,0,0,0)
#define MFMAH(a,b,c)  __builtin_amdgcn_mfma_f32_16x16x32_f16(a,b,c,0,0,0)

// ---------- helpers ----------
__device__ __forceinline__ float umt(unsigned u){
  return __uint_as_float((u & 0x80000000u) ? (u & 0x7fffffffu) : ~u);
}
__device__ __forceinline__ float wmin_f(float v){
  #pragma unroll
  for (int m=1;m<64;m<<=1) v = fminf(v, __shfl_xor(v,m,64));
  return v;
}
__device__ __forceinline__ int mbcnt64(unsigned long long m){
  return (int)__builtin_amdgcn_mbcnt_hi((unsigned)(m>>32),
         __builtin_amdgcn_mbcnt_lo((unsigned)(m & 0xffffffffull), 0u));
}
__device__ __forceinline__ short8 ldb8(const __hip_bfloat16* p){
  return *(const short8*)p;
}

// full-register 32-bit bisection + v205 recovery (exact, rare fallback)
#define FULLSEL(SU, V206, V205)                                                \
  {                                                                            \
    unsigned v = 0u;                                                           \
    _Pragma("unroll 1")                                                        \
    for (int bit = 31; bit >= 0; --bit){                                       \
      const float cf = umt(v | (1u << bit));                                   \
      int n = 0;                                                               \
      _Pragma("unroll")                                                        \
      for (int i = 0; i < 32; i++) n += (int)__popcll(__ballot(SU[i] >= cf));  \
      if (n >= 206) v |= (1u << bit);                                          \
    }                                                                          \
    V206 = umt(v);                                                             \
    int cgt = 0; float mn = 3.0e38f;                                           \
    _Pragma("unroll")                                                          \
    for (int i = 0; i < 32; i++){                                              \
      const float u = SU[i];                                                   \
      const bool gt = (u > V206);                                              \
      cgt += (int)__popcll(__ballot(gt));                                      \
      mn = (gt && u < mn) ? u : mn;                                            \
    }                                                                          \
    mn = wmin_f(mn);                                                           \
    V205 = (cgt == 205) ? mn : V206;                                           \
  }

// ---------- K0a: column-sum partials of x + bf16 hi/lo split ----------
__global__ void xpart_kernel(const float* __restrict__ x, float* __restrict__ xpart,
                             __hip_bfloat16* __restrict__ xh, __hip_bfloat16* __restrict__ xl){
  const int ch = blockIdx.x, b = blockIdx.y, t = threadIdx.x;   // ch in [0,128)
  const size_t base = ((size_t)b*2048 + (size_t)ch*16)*256 + t;
  float s = 0.f;
  #pragma unroll
  for (int i=0;i<16;i++){
    const float v = x[base + (size_t)i*256];
    s += v;
    const __hip_bfloat16 h = __float2bfloat16(v);
    xh[base + (size_t)i*256] = h;
    xl[base + (size_t)i*256] = __float2bfloat16(v - __bfloat162float(h));
  }
  xpart[(size_t)(b*128+ch)*256 + t] = s;
}

// ---------- K0c: weight bf16 hi/lo split (Wq,Wk,Wv,Wo -> [mat][256][256]) ----------
__global__ void wconv_kernel(const float* __restrict__ Wq, const float* __restrict__ Wk,
                             const float* __restrict__ Wv, const float* __restrict__ Wo,
                             __hip_bfloat16* __restrict__ wh, __hip_bfloat16* __restrict__ wl){
  const int mat = blockIdx.x >> 6;
  const float* W = (mat==0) ? Wq : (mat==1) ? Wk : (mat==2) ? Wv : Wo;
  const int off = (blockIdx.x & 63)*1024 + threadIdx.x*4;
  const float4 v = *(const float4*)&W[off];
  const float vv[4] = {v.x, v.y, v.z, v.w};
  short hs[4], ls[4];
  #pragma unroll
  for (int i=0;i<4;i++){
    const __hip_bfloat16 h = __float2bfloat16(vv[i]);
    const __hip_bfloat16 l = __float2bfloat16(vv[i] - __bfloat162float(h));
    hs[i] = *(const short*)&h; ls[i] = *(const short*)&l;
  }
  const size_t o = (size_t)mat*65536 + off;
  *(short4*)((short*)wh + o) = make_short4(hs[0],hs[1],hs[2],hs[3]);
  *(short4*)((short*)wl + o) = make_short4(ls[0],ls[1],ls[2],ls[3]);
}

// ---------- K0b: gate[b][256], one block per batch, parallel matvec ----------
__global__ void gate_kernel(const float* __restrict__ xpart,
                            const float* __restrict__ Wg, const float* __restrict__ bg,
                            const float* __restrict__ Wgp,const float* __restrict__ bgp,
                            float* __restrict__ gate_ws){
  __shared__ float xm[256];
  __shared__ float part[16][17];
  __shared__ float g16[16];
  const int t = threadIdx.x;
  const int b = blockIdx.x;
  float s = 0.f;
  for (int ch=0; ch<128; ch++) s += xpart[(size_t)(b*128+ch)*256 + t];
  xm[t] = s * (1.0f/2048.0f);
  __syncthreads();
  {
    const int j = t >> 4, dg = t & 15;
    float p = 0.f;
    #pragma unroll
    for (int d=0; d<16; d++) p = fmaf(xm[dg*16+d], Wg[j*256 + dg*16 + d], p);
    part[j][dg] = p;
  }
  __syncthreads();
  if (t < 16){
    float z = bg[t];
    #pragma unroll
    for (int g=0; g<16; g++) z += part[t][g];
    g16[t] = 1.0f/(1.0f + __expf(-z));
  }
  __syncthreads();
  float z2 = bgp[t];
  #pragma unroll
  for (int j=0;j<16;j++) z2 = fmaf(g16[j], Wgp[t*16+j], z2);
  gate_ws[b*256 + t] = z2;
}

// ---------- K1: fused QKV projection, LDS-staged bf16 hi/lo MFMA (pre-converted) ----------
__global__ __launch_bounds__(256) void qkv_gemm(
    const __hip_bfloat16* __restrict__ xh, const __hip_bfloat16* __restrict__ xl,
    const __hip_bfloat16* __restrict__ wh, const __hip_bfloat16* __restrict__ wl,
    const float* __restrict__ bq, const float* __restrict__ bk, const float* __restrict__ bv,
    __hip_bfloat16* __restrict__ qh, __hip_bfloat16* __restrict__ ql,
    __hip_bfloat16* __restrict__ kh, __hip_bfloat16* __restrict__ kl,
    _Float16* __restrict__ vth, _Float16* __restrict__ vtl){
  __shared__ short Ah[64][40], Al[64][40];   // 80B rows: 16B-aligned, bank stride 20
  __shared__ short Bh[64][40], Bl[64][40];
  const int m0 = blockIdx.x * 64;
  const int n0g = blockIdx.y * 64;          // global col tile in [0,768)
  const int sect = n0g >> 8;                // 0:Q 1:K 2:V
  const int nl0 = n0g & 255;
  const __hip_bfloat16* Wh = wh + (size_t)sect*65536;
  const __hip_bfloat16* Wl = wl + (size_t)sect*65536;
  const float* bias = (sect==0) ? bq : ((sect==1) ? bk : bv);
  const int tid = threadIdx.x;
  const int lr = tid >> 2, lc = tid & 3;
  const int w = tid >> 6, ln = tid & 63;
  const int lm = ln & 15, lk = (ln >> 4) * 8;

  floatx4 acc[4];
  #pragma unroll
  for (int tl=0;tl<4;tl++) acc[tl] = (floatx4){0.f,0.f,0.f,0.f};

  for (int k0 = 0; k0 < 256; k0 += 32){
    const short8 a_h = ldb8(xh + (size_t)(m0 +lr)*256 + k0 + lc*8);
    const short8 a_l = ldb8(xl + (size_t)(m0 +lr)*256 + k0 + lc*8);
    const short8 b_h = ldb8(Wh + (size_t)(nl0+lr)*256 + k0 + lc*8);
    const short8 b_l = ldb8(Wl + (size_t)(nl0+lr)*256 + k0 + lc*8);
    __syncthreads();                       // previous iter frag reads done
    *(short8*)&Ah[lr][lc*8] = a_h;
    *(short8*)&Al[lr][lc*8] = a_l;
    *(short8*)&Bh[lr][lc*8] = b_h;
    *(short8*)&Bl[lr][lc*8] = b_l;
    __syncthreads();                       // staged tile visible
    const short8 ah8 = *(const short8*)&Ah[w*16+lm][lk];
    const short8 al8 = *(const short8*)&Al[w*16+lm][lk];
    #pragma unroll
    for (int tl = 0; tl < 4; tl++){
      const short8 bh8 = *(const short8*)&Bh[tl*16+lm][lk];
      const short8 bl8 = *(const short8*)&Bl[tl*16+lm][lk];
      acc[tl] = MFMA16(ah8, bh8, acc[tl]);
      acc[tl] = MFMA16(al8, bh8, acc[tl]);
      acc[tl] = MFMA16(ah8, bl8, acc[tl]);
      acc[tl] = MFMA16(al8, bl8, acc[tl]);
    }
  }

  // D layout: row = (ln>>4)*4 + i (M), col = ln&15 (N)
  #pragma unroll
  for (int tl = 0; tl < 4; tl++){
    const int f = nl0 + tl*16 + lm;        // feature in [0,256)
    const int hh = f >> 6, hd = f & 63;
    const float bf = bias[f];
    if (sect == 2){
      const int mB = m0 + w*16 + (ln >> 4)*4;  // 4 consecutive s values
      const int bidx = mB >> 11, s0 = mB & 2047;
      half4v hv, lv;
      #pragma unroll
      for (int i=0;i<4;i++){
        const float val = acc[tl][i] + bf;
        const _Float16 hx = (_Float16)val;
        hv[i] = hx;
        lv[i] = (_Float16)(val - (float)hx);
      }
      const size_t row = (size_t)((bidx*4+hh)*64 + hd);
      *(half4v*)(vth + row*2048 + s0) = hv;
      *(half4v*)(vtl + row*2048 + s0) = lv;
    } else {
      #pragma unroll
      for (int i=0;i<4;i++){
        const int m = m0 + w*16 + (ln >> 4)*4 + i;
        const int bidx = m >> 11, s = m & 2047;
        const float val = acc[tl][i] + bf;
        const size_t idx = (size_t)((bidx*4+hh)*2048 + s)*64 + hd;
        const __hip_bfloat16 hi = __float2bfloat16(val);
        const float lo = val - __bfloat162float(hi);
        if (sect == 0){ qh[idx] = hi; ql[idx] = __float2bfloat16(lo); }
        else          { kh[idx] = hi; kl[idx] = __float2bfloat16(lo); }
      }
    }
  }
}

// ---------- K2: sparse attention + fused distill/gate mix ----------
// smem map (70336 B, 2 blocks/CU — reg-capped anyway):
//  [0, 33024)      buf0: score chunks 0,2   | later: P-half [16][1024] f16 (32KB)
//  [33024, 66048)  buf1: score chunks 1,3   | later: cand scratch (16x1KB)
//  [66048, 70272)  obuf[16][66] cross-quarter PV reduce
//  [70272, 70336)  zbuf[16]
__global__ __launch_bounds__(512, 4) void attn_kernel(
    const __hip_bfloat16* __restrict__ qh, const __hip_bfloat16* __restrict__ ql,
    const __hip_bfloat16* __restrict__ kh, const __hip_bfloat16* __restrict__ kl,
    const _Float16* __restrict__ vth, const _Float16* __restrict__ vtl,
    const float* __restrict__ Wd, const float* __restrict__ bd,
    const float* __restrict__ gate_ws,
    __hip_bfloat16* __restrict__ mixh, __hip_bfloat16* __restrict__ mixl){
  __shared__ __align__(16) char smem[70336];
  float (*buf0)[516] = (float (*)[516])smem;
  float (*buf1)[516] = (float (*)[516])(smem + 33024);
  float (*obuf)[66] = (float (*)[66])(smem + 66048);
  float* zbuf = (float*)(smem + 70272);

  const int bh = blockIdx.y;
  const int q0 = blockIdx.x * 16;
  const int tid = threadIdx.x;
  const int w = tid >> 6, ln = tid & 63;
  const int lm = ln & 15;
  const int lk = (ln >> 4) * 8;
  const int qa = 2*w, qb = 2*w + 1;

  const __hip_bfloat16* Qh = qh + ((size_t)bh*2048 + q0)*64;
  const __hip_bfloat16* Ql = ql + ((size_t)bh*2048 + q0)*64;
  const __hip_bfloat16* Kh = kh + ((size_t)bh*2048 + w*256)*64;
  const __hip_bfloat16* Kl = kl + ((size_t)bh*2048 + w*256)*64;

  float su0[32], su1[32];

  // Q fragments are chunk-invariant: hoist.
  const short8 ah0 = ldb8(Qh + lm*64 + lk);
  const short8 ah1 = ldb8(Qh + lm*64 + 32 + lk);
  const short8 al0 = ldb8(Ql + lm*64 + lk);
  const short8 al1 = ldb8(Ql + lm*64 + 32 + lk);

  // ----- rounds: MFMA 4 tiles -> ping-pong LDS handoff (1 barrier/chunk) -----
  #pragma unroll
  for (int c = 0; c < 4; c++){
    float (*bufc)[516] = (c & 1) ? buf1 : buf0;
    floatx4 acc[4];
    #pragma unroll
    for (int tl = 0; tl < 4; tl++){
      const int krow = c*64 + tl*16 + lm;
      short8 bh0 = ldb8(Kh + krow*64 + lk);
      short8 bh1 = ldb8(Kh + krow*64 + 32 + lk);
      short8 bl0 = ldb8(Kl + krow*64 + lk);
      short8 bl1 = ldb8(Kl + krow*64 + 32 + lk);
      floatx4 a = {0.f,0.f,0.f,0.f};
      a = MFMA16(ah0, bh0, a);
      a = MFMA16(ah1, bh1, a);
      a = MFMA16(al0, bh0, a);
      a = MFMA16(al1, bh1, a);
      a = MFMA16(ah0, bl0, a);
      a = MFMA16(ah1, bl1, a);
      a = MFMA16(al0, bl0, a);
      a = MFMA16(al1, bl1, a);
      acc[tl] = a;
    }
    const int wr = (ln >> 4) * 4;         // C-layout: row=(lane>>4)*4+reg, col=lane&15
    #pragma unroll
    for (int tl = 0; tl < 4; tl++){
      const int col = w*64 + tl*16 + lm;
      bufc[wr+0][col] = acc[tl].x * 0.125f;
      bufc[wr+1][col] = acc[tl].y * 0.125f;
      bufc[wr+2][col] = acc[tl].z * 0.125f;
      bufc[wr+3][col] = acc[tl].w * 0.125f;
    }
    __syncthreads();                      // chunk c visible; c-1 readers all done
    float4 ra0 = *(const float4*)&bufc[qa][4*ln];
    float4 ra1 = *(const float4*)&bufc[qa][256 + 4*ln];
    float4 rb0 = *(const float4*)&bufc[qb][4*ln];
    float4 rb1 = *(const float4*)&bufc[qb][256 + 4*ln];
    const int o = c*8;
    su0[o+0]=ra0.x; su0[o+1]=ra0.y; su0[o+2]=ra0.z; su0[o+3]=ra0.w;
    su0[o+4]=ra1.x; su0[o+5]=ra1.y; su0[o+6]=ra1.z; su0[o+7]=ra1.w;
    su1[o+0]=rb0.x; su1[o+1]=rb0.y; su1[o+2]=rb0.z; su1[o+3]=rb0.w;
    su1[o+4]=rb1.x; su1[o+5]=rb1.y; su1[o+6]=rb1.z; su1[o+7]=rb1.w;
  }
  __syncthreads();   // chunk-3 reads (buf1) done; buf1 region free for cand
  // su index i (chunk c=i>>3, m=i&7) -> key:
  //   key = (ln>>4)*256 + ((m&4)<<8) + c*64 + (ln&15)*4 + (m&3)
  //   (m&4) selects key-half: i = c*8 + hp*4 + jj covers half hp.

  // ----- pass A: per-row mean/std/max (scores ~iid normal per row) -----
  float sm0 = 0.f, sm1 = 0.f, sq0 = 0.f, sq1 = 0.f;
  float mx0 = -3.0e38f, mx1 = -3.0e38f;
  #pragma unroll
  for (int i = 0; i < 32; i++){
    const float u0 = su0[i], u1 = su1[i];
    sm0 += u0; sm1 += u1;
    sq0 = fmaf(u0, u0, sq0); sq1 = fmaf(u1, u1, sq1);
    mx0 = fmaxf(mx0, u0); mx1 = fmaxf(mx1, u1);
  }
  #pragma unroll
  for (int m=1;m<64;m<<=1){
    sm0 += __shfl_xor(sm0,m,64); sm1 += __shfl_xor(sm1,m,64);
    sq0 += __shfl_xor(sq0,m,64); sq1 += __shfl_xor(sq1,m,64);
    mx0 = fmaxf(mx0, __shfl_xor(mx0,m,64));
    mx1 = fmaxf(mx1, __shfl_xor(mx1,m,64));
  }
  const float mean0 = sm0 * (1.f/2048.f), mean1 = sm1 * (1.f/2048.f);
  const float sd0 = sqrtf(fmaxf(sq0*(1.f/2048.f) - mean0*mean0, 0.f));
  const float sd1 = sqrtf(fmaxf(sq1*(1.f/2048.f) - mean1*mean1, 0.f));
  const float lo0 = mean0 + sd0, lo1 = mean1 + sd1;               // ~rank 325
  const float hi0 = fmaf(1.5f, sd0, mean0), hi1 = fmaf(1.5f, sd1, mean1); // ~rank 137

  const int b = bh >> 2, h = bh & 3;

  // ----- pass B: above-count, min-above, compact candidates in [lo,hi) -----
  float* cand0 = (float*)(smem + 33024 + (size_t)w*2048);
  float* cand1 = (float*)(smem + 33024 + (size_t)w*2048 + 1024);

  int above0 = 0, nc0 = 0, above1 = 0, nc1 = 0;
  float mnab0 = 3.0e38f, mnab1 = 3.0e38f;
  #pragma unroll
  for (int i = 0; i < 32; i++){
    const float u0 = su0[i], u1 = su1[i];
    const bool ab0 = (u0 >= hi0), ab1 = (u1 >= hi1);
    above0 += ab0 ? 1 : 0;                 // VALU per-lane
    above1 += ab1 ? 1 : 0;
    if (ab0) mnab0 = fminf(mnab0, u0);
    if (ab1) mnab1 = fminf(mnab1, u1);
    const bool cd0 = (u0 >= lo0) && !ab0, cd1 = (u1 >= lo1) && !ab1;
    const unsigned long long bal0 = __ballot(cd0);
    if (cd0){
      const int pos = nc0 + mbcnt64(bal0);
      if (pos < CAP) cand0[pos] = u0;
    }
    nc0 += (int)__popcll(bal0);
    const unsigned long long bal1 = __ballot(cd1);
    if (cd1){
      const int pos = nc1 + mbcnt64(bal1);
      if (pos < CAP) cand1[pos] = u1;
    }
    nc1 += (int)__popcll(bal1);
  }
  int ab01 = above0 | (above1 << 16);      // packed cross-lane reduce
  #pragma unroll
  for (int m=1;m<64;m<<=1){
    ab01  += __shfl_xor(ab01, m,64);
    mnab0 = fminf(mnab0, __shfl_xor(mnab0,m,64));
    mnab1 = fminf(mnab1, __shfl_xor(mnab1,m,64));
  }
  above0 = ab01 & 0xffff;
  above1 = ab01 >> 16;

  const bool vld0 = (above0 < 206) && (above0 + nc0 >= 206) && (nc0 <= CAP);
  const bool vld1 = (above1 < 206) && (above1 + nc1 >= 206) && (nc1 <= CAP);

  float v206_0, v205_0, v206_1, v205_1;
  if (__builtin_expect(vld0 && vld1, 1)){
    // rank-j bisection over candidates, exact across the full 32-bit range:
    // cf<lo -> count=nc>=j (set); cf>=hi -> 0<j (clear); else exact in-bracket.
    const int j0 = 206 - above0, j1 = 206 - above1;
    const float cv00 = (ln       < nc0) ? cand0[ln]       : -3.0e38f;
    const float cv01 = (ln + 64  < nc0) ? cand0[ln + 64]  : -3.0e38f;
    const float cv02 = (ln + 128 < nc0) ? cand0[ln + 128] : -3.0e38f;
    const float cv03 = (ln + 192 < nc0) ? cand0[ln + 192] : -3.0e38f;
    const float cv10 = (ln       < nc1) ? cand1[ln]       : -3.0e38f;
    const float cv11 = (ln + 64  < nc1) ? cand1[ln + 64]  : -3.0e38f;
    const float cv12 = (ln + 128 < nc1) ? cand1[ln + 128] : -3.0e38f;
    const float cv13 = (ln + 192 < nc1) ? cand1[ln + 192] : -3.0e38f;
    unsigned v0 = 0u, v1 = 0u;
    #pragma unroll 1
    for (int bit = 31; bit >= 0; --bit){
      const float cf0 = umt(v0 | (1u << bit));
      const float cf1 = umt(v1 | (1u << bit));
      const int n0 = (int)__popcll(__ballot(cv00 >= cf0))
                   + (int)__popcll(__ballot(cv01 >= cf0))
                   + (int)__popcll(__ballot(cv02 >= cf0))
                   + (int)__popcll(__ballot(cv03 >= cf0));
      const int n1 = (int)__popcll(__ballot(cv10 >= cf1))
                   + (int)__popcll(__ballot(cv11 >= cf1))
                   + (int)__popcll(__ballot(cv12 >= cf1))
                   + (int)__popcll(__ballot(cv13 >= cf1));
      if (n0 >= j0) v0 |= (1u << bit);
      if (n1 >= j1) v1 |= (1u << bit);
    }
    v206_0 = umt(v0);
    v206_1 = umt(v1);
    const int cgtc0 = (int)__popcll(__ballot(cv00 > v206_0))
                    + (int)__popcll(__ballot(cv01 > v206_0))
                    + (int)__popcll(__ballot(cv02 > v206_0))
                    + (int)__popcll(__ballot(cv03 > v206_0));
    const int cgtc1 = (int)__popcll(__ballot(cv10 > v206_1))
                    + (int)__popcll(__ballot(cv11 > v206_1))
                    + (int)__popcll(__ballot(cv12 > v206_1))
                    + (int)__popcll(__ballot(cv13 > v206_1));
    float mnc0 = 3.0e38f, mnc1 = 3.0e38f;
    if (cv00 > v206_0) mnc0 = fminf(mnc0, cv00);
    if (cv01 > v206_0) mnc0 = fminf(mnc0, cv01);
    if (cv02 > v206_0) mnc0 = fminf(mnc0, cv02);
    if (cv03 > v206_0) mnc0 = fminf(mnc0, cv03);
    if (cv10 > v206_1) mnc1 = fminf(mnc1, cv10);
    if (cv11 > v206_1) mnc1 = fminf(mnc1, cv11);
    if (cv12 > v206_1) mnc1 = fminf(mnc1, cv12);
    if (cv13 > v206_1) mnc1 = fminf(mnc1, cv13);
    #pragma unroll
    for (int m=1;m<64;m<<=1){
      mnc0 = fminf(mnc0, __shfl_xor(mnc0,m,64));
      mnc1 = fminf(mnc1, __shfl_xor(mnc1,m,64));
    }
    const int cgt0 = above0 + cgtc0, cgt1 = above1 + cgtc1;
    v205_0 = (cgt0 == 205) ? ((cgtc0 > 0) ? mnc0 : mnab0) : v206_0;
    v205_1 = (cgt1 == 205) ? ((cgtc1 > 0) ? mnc1 : mnab1) : v206_1;
  } else {
    FULLSEL(su0, v206_0, v205_0);
    FULLSEL(su1, v206_1, v205_1);
  }

  const float thr0 = (float)((double)v206_0 + 0.3*((double)v205_0 - (double)v206_0));
  const float thr1 = (float)((double)v206_1 + 0.3*((double)v205_1 - (double)v206_1));

  // ----- probs + PV, two 1024-key halves in buf0's region (no barrier needed:
  //       buf0 reads ended before the post-loop barrier; cand is in buf1) -----
  float zl0 = 0.f, zl1 = 0.f;
  char* rba = smem + (size_t)qa*2048 + ((size_t)(ln >> 4) << 9)
            + (size_t)((((ln & 15) << 3)) ^ ((qa & 7) << 4));
  char* rbb = smem + (size_t)qb*2048 + ((size_t)(ln >> 4) << 9)
            + (size_t)((((ln & 15) << 3)) ^ ((qb & 7) << 4));

  // PV wave split: ct = w&3 -> dim tile, khq = w>>2 -> 512-key quarter per half
  const int ct = w & 3, khq = w >> 2;
  const int arow = ln & 15;
  const int sw = (arow & 7) << 4;       // involution on byte bits 4-6
  const char* prow = smem + (size_t)arow*2048;
  const int klog0 = (khq << 10) + ((ln >> 4) << 4);
  floatx4 acch = {0.f,0.f,0.f,0.f};
  floatx4 accl = {0.f,0.f,0.f,0.f};

  #pragma unroll
  for (int hp = 0; hp < 2; hp++){
    // dense probs for key-half hp: p = s>=thr ? exp(s-mx) : 0 -> f16
    #pragma unroll
    for (int c = 0; c < 4; c++){
      half4v pk0, pk1;
      #pragma unroll
      for (int jj = 0; jj < 4; jj++){
        const int i = c*8 + hp*4 + jj;
        const float s0 = su0[i], s1 = su1[i];
        const float pr0 = (s0 >= thr0) ? __expf(s0 - mx0) : 0.f;
        const float pr1 = (s1 >= thr1) ? __expf(s1 - mx1) : 0.f;
        const _Float16 ph0 = (_Float16)pr0;
        const _Float16 ph1 = (_Float16)pr1;
        zl0 += (float)ph0;                // Z from f16-rounded p for consistency
        zl1 += (float)ph1;
        pk0[jj] = ph0;
        pk1[jj] = ph1;
      }
      *(half4v*)(rba + c*128) = pk0;
      *(half4v*)(rbb + c*128) = pk1;
    }
    if (hp == 1){
      #pragma unroll
      for (int m=1;m<64;m<<=1){
        zl0 += __shfl_xor(zl0,m,64);
        zl1 += __shfl_xor(zl1,m,64);
      }
      if (ln == 0){ zbuf[qa] = 1.0f / zl0; zbuf[qb] = 1.0f / zl1; }
    }
    __syncthreads();   // P half hp (+zbuf at hp==1) visible

    const _Float16* vhp_ = vth + ((size_t)bh*64 + ct*16 + arow)*2048
                         + (hp << 10) + (khq << 9) + ((ln >> 4) << 3);
    const _Float16* vlp_ = vtl + ((size_t)bh*64 + ct*16 + arow)*2048
                         + (hp << 10) + (khq << 9) + ((ln >> 4) << 3);
    #pragma unroll 4
    for (int kk = 0; kk < 16; kk++){
      const half8 a   = *(const half8*)(prow + ((klog0 + kk*64) ^ sw));
      const half8 vh8 = *(const half8*)(vhp_ + kk*32);
      const half8 vl8 = *(const half8*)(vlp_ + kk*32);
      acch = MFMAH(a, vh8, acch);
      accl = MFMAH(a, vl8, accl);
    }
    if (hp == 0) __syncthreads();   // P half0 reads done before overwrite
  }
  floatx4 acc = acch + accl;

  // distill params for khq==0 waves (loads overlap the obuf barrier)
  float gt = 0.f, bda = 0.f;
  float wdv[16];
  if (khq == 1){
    const int r0 = (ln >> 4) * 4;
    #pragma unroll
    for (int i = 0; i < 4; i++) obuf[r0+i][ct*16 + arow] = acc[i];
  } else {
    gt  = gate_ws[(size_t)b*256 + h*64 + ct*16 + arow];
    bda = bd[arow];
    #pragma unroll
    for (int m4 = 0; m4 < 4; m4++){
      const float4 t4 = *(const float4*)&Wd[arow*16 + m4*4];
      wdv[m4*4+0]=t4.x; wdv[m4*4+1]=t4.y; wdv[m4*4+2]=t4.z; wdv[m4*4+3]=t4.w;
    }
  }
  __syncthreads();
  if (khq == 0){
    const int r0 = (ln >> 4) * 4;
    const int gb = ln & 48;              // 16-lane group base = distill group
    #pragma unroll
    for (int i = 0; i < 4; i++){
      const int r = r0 + i;
      const float o = (acc[i] + obuf[r][ct*16 + arow]) * zbuf[r];
      float d = bda;
      #pragma unroll
      for (int m = 0; m < 16; m++)
        d = fmaf(__shfl(o, gb + m, 64), wdv[m], d);
      const float mixed = gt*d + (1.0f - gt)*o;
      const size_t oidx = (size_t)(b*2048 + q0 + r)*256 + h*64 + ct*16 + arow;
      const __hip_bfloat16 mhv = __float2bfloat16(mixed);
      mixh[oidx] = mhv;
      mixl[oidx] = __float2bfloat16(mixed - __bfloat162float(mhv));
    }
  }
}

// ---------- K4: out = mixed @ Wo^T + bo, LDS-staged bf16 hi/lo MFMA ----------
__global__ __launch_bounds__(256) void out_gemm(
    const __hip_bfloat16* __restrict__ mh, const __hip_bfloat16* __restrict__ ml,
    const __hip_bfloat16* __restrict__ wh, const __hip_bfloat16* __restrict__ wl,
    const float* __restrict__ bo, float* __restrict__ out){
  __shared__ short Ah[64][40], Al[64][40];
  __shared__ short Bh[64][40], Bl[64][40];
  const int m0 = blockIdx.x * 64;
  const int n0 = blockIdx.y * 64;
  const __hip_bfloat16* Wh = wh + (size_t)3*65536;   // Wo at mat slot 3
  const __hip_bfloat16* Wl = wl + (size_t)3*65536;
  const int tid = threadIdx.x;
  const int lr = tid >> 2, lc = tid & 3;
  const int w = tid >> 6, ln = tid & 63;
  const int lm = ln & 15, lk = (ln >> 4) * 8;

  floatx4 acc[4];
  #pragma unroll
  for (int tl=0;tl<4;tl++) acc[tl] = (floatx4){0.f,0.f,0.f,0.f};

  for (int k0 = 0; k0 < 256; k0 += 32){
    const short8 a_h = ldb8(mh + (size_t)(m0+lr)*256 + k0 + lc*8);
    const short8 a_l = ldb8(ml + (size_t)(m0+lr)*256 + k0 + lc*8);
    const short8 b_h = ldb8(Wh + (size_t)(n0+lr)*256 + k0 + lc*8);
    const short8 b_l = ldb8(Wl + (size_t)(n0+lr)*256 + k0 + lc*8);
    __syncthreads();
    *(short8*)&Ah[lr][lc*8] = a_h;
    *(short8*)&Al[lr][lc*8] = a_l;
    *(short8*)&Bh[lr][lc*8] = b_h;
    *(short8*)&Bl[lr][lc*8] = b_l;
    __syncthreads();
    const short8 ah8 = *(const short8*)&Ah[w*16+lm][lk];
    const short8 al8 = *(const short8*)&Al[w*16+lm][lk];
    #pragma unroll
    for (int tl = 0; tl < 4; tl++){
      const short8 bh8 = *(const short8*)&Bh[tl*16+lm][lk];
      const short8 bl8 = *(const short8*)&Bl[tl*16+lm][lk];
      acc[tl] = MFMA16(ah8, bh8, acc[tl]);
      acc[tl] = MFMA16(al8, bh8, acc[tl]);
      acc[tl] = MFMA16(ah8, bl8, acc[tl]);
      acc[tl] = MFMA16(al8, bl8, acc[tl]);
    }
  }

  #pragma unroll
  for (int tl = 0; tl < 4; tl++){
    const int f = n0 + tl*16 + lm;
    const float bf = bo[f];
    #pragma unroll
    for (int i=0;i<4;i++){
      const int m = m0 + w*16 + (ln >> 4)*4 + i;
      out[(size_t)m*256 + f] = acc[tl][i] + bf;
    }
  }
}

// ---------- launch ----------
extern "C" void kernel_launch(void* const* d_in, const int* in_sizes, int n_in,
                              void* d_out, int out_size, void* d_ws, size_t ws_size,
                              hipStream_t stream) {
  const float* x   = (const float*)d_in[0];
  const float* Wq  = (const float*)d_in[1];  const float* bq  = (const float*)d_in[2];
  const float* Wk  = (const float*)d_in[3];  const float* bk  = (const float*)d_in[4];
  const float* Wv  = (const float*)d_in[5];  const float* bv  = (const float*)d_in[6];
  const float* Wd  = (const float*)d_in[7];  const float* bd  = (const float*)d_in[8];
  const float* Wg  = (const float*)d_in[9];  const float* bg  = (const float*)d_in[10];
  const float* Wgp = (const float*)d_in[11]; const float* bgp = (const float*)d_in[12];
  const float* Wo  = (const float*)d_in[13]; const float* bo  = (const float*)d_in[14];

  char* base = (char*)d_ws;
  __hip_bfloat16* mixh = (__hip_bfloat16*)(base);                   // 4 MB
  __hip_bfloat16* mixl = (__hip_bfloat16*)(base + (size_t)( 4<<20));// 4 MB
  __hip_bfloat16* qh = (__hip_bfloat16*)(base + (size_t)( 8<<20));  // 4 MB
  __hip_bfloat16* ql = (__hip_bfloat16*)(base + (size_t)(12<<20));  // 4 MB
  __hip_bfloat16* kh = (__hip_bfloat16*)(base + (size_t)(16<<20));  // 4 MB
  __hip_bfloat16* kl = (__hip_bfloat16*)(base + (size_t)(20<<20));  // 4 MB
  _Float16* vth = (_Float16*)(base + (size_t)(24<<20));             // 4 MB (V^T hi)
  _Float16* vtl = (_Float16*)(base + (size_t)(28<<20));             // 4 MB (V^T lo)
  __hip_bfloat16* xh = (__hip_bfloat16*)(base + (size_t)(32<<20));  // 4 MB
  __hip_bfloat16* xl = (__hip_bfloat16*)(base + (size_t)(36<<20));  // 4 MB
  __hip_bfloat16* wh = (__hip_bfloat16*)(base + (size_t)(40<<20));        // 512 KB
  __hip_bfloat16* wl = (__hip_bfloat16*)(base + (size_t)(40<<20) + (512<<10)); // 512 KB
  float* xpart  = (float*)(base + (size_t)(41<<20));    // 512 KB
  float* gate_ws= (float*)(base + (size_t)(41<<20) + (512<<10));

  xpart_kernel<<<dim3(128,4), 256, 0, stream>>>(x, xpart, xh, xl);
  wconv_kernel<<<256, 256, 0, stream>>>(Wq, Wk, Wv, Wo, wh, wl);
  gate_kernel<<<4, 256, 0, stream>>>(xpart, Wg, bg, Wgp, bgp, gate_ws);
  qkv_gemm<<<dim3(128,12), 256, 0, stream>>>(xh, xl, wh, wl, bq, bk, bv,
                                             qh, ql, kh, kl, vth, vtl);
  attn_kernel<<<dim3(128,16), 512, 0, stream>>>(qh, ql, kh, kl, vth, vtl,
                                                Wd, bd, gate_ws, mixh, mixl);
  out_gemm<<<dim3(128,4), 256, 0, stream>>>(mixh, mixl, wh, wl, bo, (float*)d_out);
}

// Round 14
// 372.293 us; speedup vs baseline: 1.1166x; 1.0229x over previous
//
#include <hip/hip_runtime.h>
#include <hip/hip_bf16.h>
#include <math.h>

// B=4, S=2048, D=256, H=4, HD=64; keep top-10% per score row.
// thr = v206 + 0.3*(v205 - v206)  (v_k = k-th largest), exact via bit-bisection.
//
// This round (numerics bit-identical):
//  - moment accumulation (sm/sq/mx) moved INTO the score chunk loop (same
//    i-order) -> overlaps MFMA/barriers instead of the serial selection path
//  - candidate bisection starts at the common bit-prefix of mtu(lo)/mtu(hi)
//    (~22 rounds instead of 32); bits above a row's own prefix are provable
//    no-ops, sign-straddle degenerates to full 32 rounds (guarded shift)
// Rest identical to round 13 (380.8 us; attn 281.6).

#define CAP 256

typedef __attribute__((ext_vector_type(8))) short short8;
typedef __attribute__((ext_vector_type(4))) float floatx4;
typedef _Float16 half8 __attribute__((ext_vector_type(8)));
typedef _Float16 half4v __attribute__((ext_vector_type(4)));
#define MFMA16(a,b,c) __builtin_amdgcn_mfma_f32_16x16x32_bf16(a,b,c,0,0,0)
#define MFMAH(a,b,c)  __builtin_amdgcn_mfma_f32_16x16x32_f16(a,b,c,0,0,0)

// ---------- helpers ----------
__device__ __forceinline__ unsigned mtu(float f){
  const unsigned u = __float_as_uint(f);
  return (u & 0x80000000u) ? ~u : (u | 0x80000000u);
}
__device__ __forceinline__ float umt(unsigned u){
  return __uint_as_float((u & 0x80000000u) ? (u & 0x7fffffffu) : ~u);
}
__device__ __forceinline__ float wmin_f(float v){
  #pragma unroll
  for (int m=1;m<64;m<<=1) v = fminf(v, __shfl_xor(v,m,64));
  return v;
}
__device__ __forceinline__ int mbcnt64(unsigned long long m){
  return (int)__builtin_amdgcn_mbcnt_hi((unsigned)(m>>32),
         __builtin_amdgcn_mbcnt_lo((unsigned)(m & 0xffffffffull), 0u));
}
__device__ __forceinline__ short8 ldb8(const __hip_bfloat16* p){
  return *(const short8*)p;
}

// full-register 32-bit bisection + v205 recovery (exact, rare fallback)
#define FULLSEL(SU, V206, V205)                                                \
  {                                                                            \
    unsigned v = 0u;                                                           \
    _Pragma("unroll 1")                                                        \
    for (int bit = 31; bit >= 0; --bit){                                       \
      const float cf = umt(v | (1u << bit));                                   \
      int n = 0;                                                               \
      _Pragma("unroll")                                                        \
      for (int i = 0; i < 32; i++) n += (int)__popcll(__ballot(SU[i] >= cf));  \
      if (n >= 206) v |= (1u << bit);                                          \
    }                                                                          \
    V206 = umt(v);                                                             \
    int cgt = 0; float mn = 3.0e38f;                                           \
    _Pragma("unroll")                                                          \
    for (int i = 0; i < 32; i++){                                              \
      const float u = SU[i];                                                   \
      const bool gt = (u > V206);                                              \
      cgt += (int)__popcll(__ballot(gt));                                      \
      mn = (gt && u < mn) ? u : mn;                                            \
    }                                                                          \
    mn = wmin_f(mn);                                                           \
    V205 = (cgt == 205) ? mn : V206;                                           \
  }

// ---------- K0a: column-sum partials of x + bf16 hi/lo split ----------
__global__ void xpart_kernel(const float* __restrict__ x, float* __restrict__ xpart,
                             __hip_bfloat16* __restrict__ xh, __hip_bfloat16* __restrict__ xl){
  const int ch = blockIdx.x, b = blockIdx.y, t = threadIdx.x;   // ch in [0,128)
  const size_t base = ((size_t)b*2048 + (size_t)ch*16)*256 + t;
  float s = 0.f;
  #pragma unroll
  for (int i=0;i<16;i++){
    const float v = x[base + (size_t)i*256];
    s += v;
    const __hip_bfloat16 h = __float2bfloat16(v);
    xh[base + (size_t)i*256] = h;
    xl[base + (size_t)i*256] = __float2bfloat16(v - __bfloat162float(h));
  }
  xpart[(size_t)(b*128+ch)*256 + t] = s;
}

// ---------- K0c: weight bf16 hi/lo split (Wq,Wk,Wv,Wo -> [mat][256][256]) ----------
__global__ void wconv_kernel(const float* __restrict__ Wq, const float* __restrict__ Wk,
                             const float* __restrict__ Wv, const float* __restrict__ Wo,
                             __hip_bfloat16* __restrict__ wh, __hip_bfloat16* __restrict__ wl){
  const int mat = blockIdx.x >> 6;
  const float* W = (mat==0) ? Wq : (mat==1) ? Wk : (mat==2) ? Wv : Wo;
  const int off = (blockIdx.x & 63)*1024 + threadIdx.x*4;
  const float4 v = *(const float4*)&W[off];
  const float vv[4] = {v.x, v.y, v.z, v.w};
  short hs[4], ls[4];
  #pragma unroll
  for (int i=0;i<4;i++){
    const __hip_bfloat16 h = __float2bfloat16(vv[i]);
    const __hip_bfloat16 l = __float2bfloat16(vv[i] - __bfloat162float(h));
    hs[i] = *(const short*)&h; ls[i] = *(const short*)&l;
  }
  const size_t o = (size_t)mat*65536 + off;
  *(short4*)((short*)wh + o) = make_short4(hs[0],hs[1],hs[2],hs[3]);
  *(short4*)((short*)wl + o) = make_short4(ls[0],ls[1],ls[2],ls[3]);
}

// ---------- K0b: gate[b][256], one block per batch, parallel matvec ----------
__global__ void gate_kernel(const float* __restrict__ xpart,
                            const float* __restrict__ Wg, const float* __restrict__ bg,
                            const float* __restrict__ Wgp,const float* __restrict__ bgp,
                            float* __restrict__ gate_ws){
  __shared__ float xm[256];
  __shared__ float part[16][17];
  __shared__ float g16[16];
  const int t = threadIdx.x;
  const int b = blockIdx.x;
  float s = 0.f;
  for (int ch=0; ch<128; ch++) s += xpart[(size_t)(b*128+ch)*256 + t];
  xm[t] = s * (1.0f/2048.0f);
  __syncthreads();
  {
    const int j = t >> 4, dg = t & 15;
    float p = 0.f;
    #pragma unroll
    for (int d=0; d<16; d++) p = fmaf(xm[dg*16+d], Wg[j*256 + dg*16 + d], p);
    part[j][dg] = p;
  }
  __syncthreads();
  if (t < 16){
    float z = bg[t];
    #pragma unroll
    for (int g=0; g<16; g++) z += part[t][g];
    g16[t] = 1.0f/(1.0f + __expf(-z));
  }
  __syncthreads();
  float z2 = bgp[t];
  #pragma unroll
  for (int j=0;j<16;j++) z2 = fmaf(g16[j], Wgp[t*16+j], z2);
  gate_ws[b*256 + t] = z2;
}

// ---------- K1: fused QKV projection, LDS-staged bf16 hi/lo MFMA (pre-converted) ----------
__global__ __launch_bounds__(256) void qkv_gemm(
    const __hip_bfloat16* __restrict__ xh, const __hip_bfloat16* __restrict__ xl,
    const __hip_bfloat16* __restrict__ wh, const __hip_bfloat16* __restrict__ wl,
    const float* __restrict__ bq, const float* __restrict__ bk, const float* __restrict__ bv,
    __hip_bfloat16* __restrict__ qh, __hip_bfloat16* __restrict__ ql,
    __hip_bfloat16* __restrict__ kh, __hip_bfloat16* __restrict__ kl,
    _Float16* __restrict__ vth, _Float16* __restrict__ vtl){
  __shared__ short Ah[64][40], Al[64][40];   // 80B rows: 16B-aligned, bank stride 20
  __shared__ short Bh[64][40], Bl[64][40];
  const int m0 = blockIdx.x * 64;
  const int n0g = blockIdx.y * 64;          // global col tile in [0,768)
  const int sect = n0g >> 8;                // 0:Q 1:K 2:V
  const int nl0 = n0g & 255;
  const __hip_bfloat16* Wh = wh + (size_t)sect*65536;
  const __hip_bfloat16* Wl = wl + (size_t)sect*65536;
  const float* bias = (sect==0) ? bq : ((sect==1) ? bk : bv);
  const int tid = threadIdx.x;
  const int lr = tid >> 2, lc = tid & 3;
  const int w = tid >> 6, ln = tid & 63;
  const int lm = ln & 15, lk = (ln >> 4) * 8;

  floatx4 acc[4];
  #pragma unroll
  for (int tl=0;tl<4;tl++) acc[tl] = (floatx4){0.f,0.f,0.f,0.f};

  for (int k0 = 0; k0 < 256; k0 += 32){
    const short8 a_h = ldb8(xh + (size_t)(m0 +lr)*256 + k0 + lc*8);
    const short8 a_l = ldb8(xl + (size_t)(m0 +lr)*256 + k0 + lc*8);
    const short8 b_h = ldb8(Wh + (size_t)(nl0+lr)*256 + k0 + lc*8);
    const short8 b_l = ldb8(Wl + (size_t)(nl0+lr)*256 + k0 + lc*8);
    __syncthreads();                       // previous iter frag reads done
    *(short8*)&Ah[lr][lc*8] = a_h;
    *(short8*)&Al[lr][lc*8] = a_l;
    *(short8*)&Bh[lr][lc*8] = b_h;
    *(short8*)&Bl[lr][lc*8] = b_l;
    __syncthreads();                       // staged tile visible
    const short8 ah8 = *(const short8*)&Ah[w*16+lm][lk];
    const short8 al8 = *(const short8*)&Al[w*16+lm][lk];
    #pragma unroll
    for (int tl = 0; tl < 4; tl++){
      const short8 bh8 = *(const short8*)&Bh[tl*16+lm][lk];
      const short8 bl8 = *(const short8*)&Bl[tl*16+lm][lk];
      acc[tl] = MFMA16(ah8, bh8, acc[tl]);
      acc[tl] = MFMA16(al8, bh8, acc[tl]);
      acc[tl] = MFMA16(ah8, bl8, acc[tl]);
      acc[tl] = MFMA16(al8, bl8, acc[tl]);
    }
  }

  // D layout: row = (ln>>4)*4 + i (M), col = ln&15 (N)
  #pragma unroll
  for (int tl = 0; tl < 4; tl++){
    const int f = nl0 + tl*16 + lm;        // feature in [0,256)
    const int hh = f >> 6, hd = f & 63;
    const float bf = bias[f];
    if (sect == 2){
      const int mB = m0 + w*16 + (ln >> 4)*4;  // 4 consecutive s values
      const int bidx = mB >> 11, s0 = mB & 2047;
      half4v hv, lv;
      #pragma unroll
      for (int i=0;i<4;i++){
        const float val = acc[tl][i] + bf;
        const _Float16 hx = (_Float16)val;
        hv[i] = hx;
        lv[i] = (_Float16)(val - (float)hx);
      }
      const size_t row = (size_t)((bidx*4+hh)*64 + hd);
      *(half4v*)(vth + row*2048 + s0) = hv;
      *(half4v*)(vtl + row*2048 + s0) = lv;
    } else {
      #pragma unroll
      for (int i=0;i<4;i++){
        const int m = m0 + w*16 + (ln >> 4)*4 + i;
        const int bidx = m >> 11, s = m & 2047;
        const float val = acc[tl][i] + bf;
        const size_t idx = (size_t)((bidx*4+hh)*2048 + s)*64 + hd;
        const __hip_bfloat16 hi = __float2bfloat16(val);
        const float lo = val - __bfloat162float(hi);
        if (sect == 0){ qh[idx] = hi; ql[idx] = __float2bfloat16(lo); }
        else          { kh[idx] = hi; kl[idx] = __float2bfloat16(lo); }
      }
    }
  }
}

// ---------- K2: sparse attention + fused distill/gate mix ----------
// smem map (70336 B, 2 blocks/CU — reg-capped anyway):
//  [0, 33024)      buf0: score chunks 0,2   | later: P-half [16][1024] f16 (32KB)
//  [33024, 66048)  buf1: score chunks 1,3   | later: cand scratch (16x1KB)
//  [66048, 70272)  obuf[16][66] cross-quarter PV reduce
//  [70272, 70336)  zbuf[16]
__global__ __launch_bounds__(512, 4) void attn_kernel(
    const __hip_bfloat16* __restrict__ qh, const __hip_bfloat16* __restrict__ ql,
    const __hip_bfloat16* __restrict__ kh, const __hip_bfloat16* __restrict__ kl,
    const _Float16* __restrict__ vth, const _Float16* __restrict__ vtl,
    const float* __restrict__ Wd, const float* __restrict__ bd,
    const float* __restrict__ gate_ws,
    __hip_bfloat16* __restrict__ mixh, __hip_bfloat16* __restrict__ mixl){
  __shared__ __align__(16) char smem[70336];
  float (*buf0)[516] = (float (*)[516])smem;
  float (*buf1)[516] = (float (*)[516])(smem + 33024);
  float (*obuf)[66] = (float (*)[66])(smem + 66048);
  float* zbuf = (float*)(smem + 70272);

  const int bh = blockIdx.y;
  const int q0 = blockIdx.x * 16;
  const int tid = threadIdx.x;
  const int w = tid >> 6, ln = tid & 63;
  const int lm = ln & 15;
  const int lk = (ln >> 4) * 8;
  const int qa = 2*w, qb = 2*w + 1;

  const __hip_bfloat16* Qh = qh + ((size_t)bh*2048 + q0)*64;
  const __hip_bfloat16* Ql = ql + ((size_t)bh*2048 + q0)*64;
  const __hip_bfloat16* Kh = kh + ((size_t)bh*2048 + w*256)*64;
  const __hip_bfloat16* Kl = kl + ((size_t)bh*2048 + w*256)*64;

  float su0[32], su1[32];

  // Q fragments are chunk-invariant: hoist.
  const short8 ah0 = ldb8(Qh + lm*64 + lk);
  const short8 ah1 = ldb8(Qh + lm*64 + 32 + lk);
  const short8 al0 = ldb8(Ql + lm*64 + lk);
  const short8 al1 = ldb8(Ql + lm*64 + 32 + lk);

  // moment partials accumulate inside the chunk loop (hidden under MFMA)
  float sm0 = 0.f, sm1 = 0.f, sq0 = 0.f, sq1 = 0.f;
  float mx0 = -3.0e38f, mx1 = -3.0e38f;

  // ----- rounds: MFMA 4 tiles -> ping-pong LDS handoff (1 barrier/chunk) -----
  #pragma unroll
  for (int c = 0; c < 4; c++){
    float (*bufc)[516] = (c & 1) ? buf1 : buf0;
    floatx4 acc[4];
    #pragma unroll
    for (int tl = 0; tl < 4; tl++){
      const int krow = c*64 + tl*16 + lm;
      short8 bh0 = ldb8(Kh + krow*64 + lk);
      short8 bh1 = ldb8(Kh + krow*64 + 32 + lk);
      short8 bl0 = ldb8(Kl + krow*64 + lk);
      short8 bl1 = ldb8(Kl + krow*64 + 32 + lk);
      floatx4 a = {0.f,0.f,0.f,0.f};
      a = MFMA16(ah0, bh0, a);
      a = MFMA16(ah1, bh1, a);
      a = MFMA16(al0, bh0, a);
      a = MFMA16(al1, bh1, a);
      a = MFMA16(ah0, bl0, a);
      a = MFMA16(ah1, bl1, a);
      a = MFMA16(al0, bl0, a);
      a = MFMA16(al1, bl1, a);
      acc[tl] = a;
    }
    const int wr = (ln >> 4) * 4;         // C-layout: row=(lane>>4)*4+reg, col=lane&15
    #pragma unroll
    for (int tl = 0; tl < 4; tl++){
      const int col = w*64 + tl*16 + lm;
      bufc[wr+0][col] = acc[tl].x * 0.125f;
      bufc[wr+1][col] = acc[tl].y * 0.125f;
      bufc[wr+2][col] = acc[tl].z * 0.125f;
      bufc[wr+3][col] = acc[tl].w * 0.125f;
    }
    __syncthreads();                      // chunk c visible; c-1 readers all done
    float4 ra0 = *(const float4*)&bufc[qa][4*ln];
    float4 ra1 = *(const float4*)&bufc[qa][256 + 4*ln];
    float4 rb0 = *(const float4*)&bufc[qb][4*ln];
    float4 rb1 = *(const float4*)&bufc[qb][256 + 4*ln];
    const int o = c*8;
    su0[o+0]=ra0.x; su0[o+1]=ra0.y; su0[o+2]=ra0.z; su0[o+3]=ra0.w;
    su0[o+4]=ra1.x; su0[o+5]=ra1.y; su0[o+6]=ra1.z; su0[o+7]=ra1.w;
    su1[o+0]=rb0.x; su1[o+1]=rb0.y; su1[o+2]=rb0.z; su1[o+3]=rb0.w;
    su1[o+4]=rb1.x; su1[o+5]=rb1.y; su1[o+6]=rb1.z; su1[o+7]=rb1.w;
    #pragma unroll
    for (int jj = 0; jj < 8; jj++){       // same i-order as a post-loop scan
      const float u0 = su0[o+jj], u1 = su1[o+jj];
      sm0 += u0; sq0 = fmaf(u0, u0, sq0); mx0 = fmaxf(mx0, u0);
      sm1 += u1; sq1 = fmaf(u1, u1, sq1); mx1 = fmaxf(mx1, u1);
    }
  }
  __syncthreads();   // chunk-3 reads (buf1) done; buf1 region free for cand
  // su index i (chunk c=i>>3, m=i&7) -> key:
  //   key = (ln>>4)*256 + ((m&4)<<8) + c*64 + (ln&15)*4 + (m&3)
  //   (m&4) selects key-half: i = c*8 + hp*4 + jj covers half hp.

  // ----- moment reduce -> normal-bracket [lo,hi) around rank 206 -----
  #pragma unroll
  for (int m=1;m<64;m<<=1){
    sm0 += __shfl_xor(sm0,m,64); sm1 += __shfl_xor(sm1,m,64);
    sq0 += __shfl_xor(sq0,m,64); sq1 += __shfl_xor(sq1,m,64);
    mx0 = fmaxf(mx0, __shfl_xor(mx0,m,64));
    mx1 = fmaxf(mx1, __shfl_xor(mx1,m,64));
  }
  const float mean0 = sm0 * (1.f/2048.f), mean1 = sm1 * (1.f/2048.f);
  const float sd0 = sqrtf(fmaxf(sq0*(1.f/2048.f) - mean0*mean0, 0.f));
  const float sd1 = sqrtf(fmaxf(sq1*(1.f/2048.f) - mean1*mean1, 0.f));
  const float lo0 = mean0 + sd0, lo1 = mean1 + sd1;               // ~rank 325
  const float hi0 = fmaf(1.5f, sd0, mean0), hi1 = fmaf(1.5f, sd1, mean1); // ~rank 137

  const int b = bh >> 2, h = bh & 3;

  // ----- pass B: above-count, min-above, compact candidates in [lo,hi) -----
  float* cand0 = (float*)(smem + 33024 + (size_t)w*2048);
  float* cand1 = (float*)(smem + 33024 + (size_t)w*2048 + 1024);

  int above0 = 0, nc0 = 0, above1 = 0, nc1 = 0;
  float mnab0 = 3.0e38f, mnab1 = 3.0e38f;
  #pragma unroll
  for (int i = 0; i < 32; i++){
    const float u0 = su0[i], u1 = su1[i];
    const bool ab0 = (u0 >= hi0), ab1 = (u1 >= hi1);
    above0 += ab0 ? 1 : 0;                 // VALU per-lane
    above1 += ab1 ? 1 : 0;
    if (ab0) mnab0 = fminf(mnab0, u0);
    if (ab1) mnab1 = fminf(mnab1, u1);
    const bool cd0 = (u0 >= lo0) && !ab0, cd1 = (u1 >= lo1) && !ab1;
    const unsigned long long bal0 = __ballot(cd0);
    if (cd0){
      const int pos = nc0 + mbcnt64(bal0);
      if (pos < CAP) cand0[pos] = u0;
    }
    nc0 += (int)__popcll(bal0);
    const unsigned long long bal1 = __ballot(cd1);
    if (cd1){
      const int pos = nc1 + mbcnt64(bal1);
      if (pos < CAP) cand1[pos] = u1;
    }
    nc1 += (int)__popcll(bal1);
  }
  int ab01 = above0 | (above1 << 16);      // packed cross-lane reduce
  #pragma unroll
  for (int m=1;m<64;m<<=1){
    ab01  += __shfl_xor(ab01, m,64);
    mnab0 = fminf(mnab0, __shfl_xor(mnab0,m,64));
    mnab1 = fminf(mnab1, __shfl_xor(mnab1,m,64));
  }
  above0 = ab01 & 0xffff;
  above1 = ab01 >> 16;

  const bool vld0 = (above0 < 206) && (above0 + nc0 >= 206) && (nc0 <= CAP);
  const bool vld1 = (above1 < 206) && (above1 + nc1 >= 206) && (nc1 <= CAP);

  float v206_0, v205_0, v206_1, v205_1;
  if (__builtin_expect(vld0 && vld1, 1)){
    // rank-j bisection over candidates starting at the common prefix of
    // mtu(lo)/mtu(hi) (v206 in [lo,hi) shares it). Bits above a row's own
    // prefix are no-ops: already-set -> count>=j keeps them; clear -> count=0.
    const int j0 = 206 - above0, j1 = 206 - above1;
    const float cv00 = (ln       < nc0) ? cand0[ln]       : -3.0e38f;
    const float cv01 = (ln + 64  < nc0) ? cand0[ln + 64]  : -3.0e38f;
    const float cv02 = (ln + 128 < nc0) ? cand0[ln + 128] : -3.0e38f;
    const float cv03 = (ln + 192 < nc0) ? cand0[ln + 192] : -3.0e38f;
    const float cv10 = (ln       < nc1) ? cand1[ln]       : -3.0e38f;
    const float cv11 = (ln + 64  < nc1) ? cand1[ln + 64]  : -3.0e38f;
    const float cv12 = (ln + 128 < nc1) ? cand1[ln + 128] : -3.0e38f;
    const float cv13 = (ln + 192 < nc1) ? cand1[ln + 192] : -3.0e38f;
    const unsigned ulo0 = mtu(lo0), uhi0 = mtu(hi0);
    const unsigned ulo1 = mtu(lo1), uhi1 = mtu(hi1);
    const int kb0 = 31 - __builtin_clz((ulo0 ^ uhi0) | 1u);
    const int kb1 = 31 - __builtin_clz((ulo1 ^ uhi1) | 1u);
    unsigned v0 = (kb0 >= 31) ? 0u : (ulo0 & (0xFFFFFFFFu << (kb0+1)));
    unsigned v1 = (kb1 >= 31) ? 0u : (ulo1 & (0xFFFFFFFFu << (kb1+1)));
    const int KB = (kb0 > kb1) ? kb0 : kb1;
    #pragma unroll 1
    for (int bit = KB; bit >= 0; --bit){
      const float cf0 = umt(v0 | (1u << bit));
      const float cf1 = umt(v1 | (1u << bit));
      const int n0 = (int)__popcll(__ballot(cv00 >= cf0))
                   + (int)__popcll(__ballot(cv01 >= cf0))
                   + (int)__popcll(__ballot(cv02 >= cf0))
                   + (int)__popcll(__ballot(cv03 >= cf0));
      const int n1 = (int)__popcll(__ballot(cv10 >= cf1))
                   + (int)__popcll(__ballot(cv11 >= cf1))
                   + (int)__popcll(__ballot(cv12 >= cf1))
                   + (int)__popcll(__ballot(cv13 >= cf1));
      if (n0 >= j0) v0 |= (1u << bit);
      if (n1 >= j1) v1 |= (1u << bit);
    }
    v206_0 = umt(v0);
    v206_1 = umt(v1);
    const int cgtc0 = (int)__popcll(__ballot(cv00 > v206_0))
                    + (int)__popcll(__ballot(cv01 > v206_0))
                    + (int)__popcll(__ballot(cv02 > v206_0))
                    + (int)__popcll(__ballot(cv03 > v206_0));
    const int cgtc1 = (int)__popcll(__ballot(cv10 > v206_1))
                    + (int)__popcll(__ballot(cv11 > v206_1))
                    + (int)__popcll(__ballot(cv12 > v206_1))
                    + (int)__popcll(__ballot(cv13 > v206_1));
    float mnc0 = 3.0e38f, mnc1 = 3.0e38f;
    if (cv00 > v206_0) mnc0 = fminf(mnc0, cv00);
    if (cv01 > v206_0) mnc0 = fminf(mnc0, cv01);
    if (cv02 > v206_0) mnc0 = fminf(mnc0, cv02);
    if (cv03 > v206_0) mnc0 = fminf(mnc0, cv03);
    if (cv10 > v206_1) mnc1 = fminf(mnc1, cv10);
    if (cv11 > v206_1) mnc1 = fminf(mnc1, cv11);
    if (cv12 > v206_1) mnc1 = fminf(mnc1, cv12);
    if (cv13 > v206_1) mnc1 = fminf(mnc1, cv13);
    #pragma unroll
    for (int m=1;m<64;m<<=1){
      mnc0 = fminf(mnc0, __shfl_xor(mnc0,m,64));
      mnc1 = fminf(mnc1, __shfl_xor(mnc1,m,64));
    }
    const int cgt0 = above0 + cgtc0, cgt1 = above1 + cgtc1;
    v205_0 = (cgt0 == 205) ? ((cgtc0 > 0) ? mnc0 : mnab0) : v206_0;
    v205_1 = (cgt1 == 205) ? ((cgtc1 > 0) ? mnc1 : mnab1) : v206_1;
  } else {
    FULLSEL(su0, v206_0, v205_0);
    FULLSEL(su1, v206_1, v205_1);
  }

  const float thr0 = (float)((double)v206_0 + 0.3*((double)v205_0 - (double)v206_0));
  const float thr1 = (float)((double)v206_1 + 0.3*((double)v205_1 - (double)v206_1));

  // ----- probs + PV, two 1024-key halves in buf0's region (no barrier needed:
  //       buf0 reads ended before the post-loop barrier; cand is in buf1) -----
  float zl0 = 0.f, zl1 = 0.f;
  char* rba = smem + (size_t)qa*2048 + ((size_t)(ln >> 4) << 9)
            + (size_t)((((ln & 15) << 3)) ^ ((qa & 7) << 4));
  char* rbb = smem + (size_t)qb*2048 + ((size_t)(ln >> 4) << 9)
            + (size_t)((((ln & 15) << 3)) ^ ((qb & 7) << 4));

  // PV wave split: ct = w&3 -> dim tile, khq = w>>2 -> 512-key quarter per half
  const int ct = w & 3, khq = w >> 2;
  const int arow = ln & 15;
  const int sw = (arow & 7) << 4;       // involution on byte bits 4-6
  const char* prow = smem + (size_t)arow*2048;
  const int klog0 = (khq << 10) + ((ln >> 4) << 4);
  floatx4 acch = {0.f,0.f,0.f,0.f};
  floatx4 accl = {0.f,0.f,0.f,0.f};

  #pragma unroll
  for (int hp = 0; hp < 2; hp++){
    // dense probs for key-half hp: p = s>=thr ? exp(s-mx) : 0 -> f16
    #pragma unroll
    for (int c = 0; c < 4; c++){
      half4v pk0, pk1;
      #pragma unroll
      for (int jj = 0; jj < 4; jj++){
        const int i = c*8 + hp*4 + jj;
        const float s0 = su0[i], s1 = su1[i];
        const float pr0 = (s0 >= thr0) ? __expf(s0 - mx0) : 0.f;
        const float pr1 = (s1 >= thr1) ? __expf(s1 - mx1) : 0.f;
        const _Float16 ph0 = (_Float16)pr0;
        const _Float16 ph1 = (_Float16)pr1;
        zl0 += (float)ph0;                // Z from f16-rounded p for consistency
        zl1 += (float)ph1;
        pk0[jj] = ph0;
        pk1[jj] = ph1;
      }
      *(half4v*)(rba + c*128) = pk0;
      *(half4v*)(rbb + c*128) = pk1;
    }
    if (hp == 1){
      #pragma unroll
      for (int m=1;m<64;m<<=1){
        zl0 += __shfl_xor(zl0,m,64);
        zl1 += __shfl_xor(zl1,m,64);
      }
      if (ln == 0){ zbuf[qa] = 1.0f / zl0; zbuf[qb] = 1.0f / zl1; }
    }
    __syncthreads();   // P half hp (+zbuf at hp==1) visible

    const _Float16* vhp_ = vth + ((size_t)bh*64 + ct*16 + arow)*2048
                         + (hp << 10) + (khq << 9) + ((ln >> 4) << 3);
    const _Float16* vlp_ = vtl + ((size_t)bh*64 + ct*16 + arow)*2048
                         + (hp << 10) + (khq << 9) + ((ln >> 4) << 3);
    #pragma unroll 4
    for (int kk = 0; kk < 16; kk++){
      const half8 a   = *(const half8*)(prow + ((klog0 + kk*64) ^ sw));
      const half8 vh8 = *(const half8*)(vhp_ + kk*32);
      const half8 vl8 = *(const half8*)(vlp_ + kk*32);
      acch = MFMAH(a, vh8, acch);
      accl = MFMAH(a, vl8, accl);
    }
    if (hp == 0) __syncthreads();   // P half0 reads done before overwrite
  }
  floatx4 acc = acch + accl;

  // distill params for khq==0 waves (loads overlap the obuf barrier)
  float gt = 0.f, bda = 0.f;
  float wdv[16];
  if (khq == 1){
    const int r0 = (ln >> 4) * 4;
    #pragma unroll
    for (int i = 0; i < 4; i++) obuf[r0+i][ct*16 + arow] = acc[i];
  } else {
    gt  = gate_ws[(size_t)b*256 + h*64 + ct*16 + arow];
    bda = bd[arow];
    #pragma unroll
    for (int m4 = 0; m4 < 4; m4++){
      const float4 t4 = *(const float4*)&Wd[arow*16 + m4*4];
      wdv[m4*4+0]=t4.x; wdv[m4*4+1]=t4.y; wdv[m4*4+2]=t4.z; wdv[m4*4+3]=t4.w;
    }
  }
  __syncthreads();
  if (khq == 0){
    const int r0 = (ln >> 4) * 4;
    const int gb = ln & 48;              // 16-lane group base = distill group
    #pragma unroll
    for (int i = 0; i < 4; i++){
      const int r = r0 + i;
      const float o = (acc[i] + obuf[r][ct*16 + arow]) * zbuf[r];
      float d = bda;
      #pragma unroll
      for (int m = 0; m < 16; m++)
        d = fmaf(__shfl(o, gb + m, 64), wdv[m], d);
      const float mixed = gt*d + (1.0f - gt)*o;
      const size_t oidx = (size_t)(b*2048 + q0 + r)*256 + h*64 + ct*16 + arow;
      const __hip_bfloat16 mhv = __float2bfloat16(mixed);
      mixh[oidx] = mhv;
      mixl[oidx] = __float2bfloat16(mixed - __bfloat162float(mhv));
    }
  }
}

// ---------- K4: out = mixed @ Wo^T + bo, LDS-staged bf16 hi/lo MFMA ----------
__global__ __launch_bounds__(256) void out_gemm(
    const __hip_bfloat16* __restrict__ mh, const __hip_bfloat16* __restrict__ ml,
    const __hip_bfloat16* __restrict__ wh, const __hip_bfloat16* __restrict__ wl,
    const float* __restrict__ bo, float* __restrict__ out){
  __shared__ short Ah[64][40], Al[64][40];
  __shared__ short Bh[64][40], Bl[64][40];
  const int m0 = blockIdx.x * 64;
  const int n0 = blockIdx.y * 64;
  const __hip_bfloat16* Wh = wh + (size_t)3*65536;   // Wo at mat slot 3
  const __hip_bfloat16* Wl = wl + (size_t)3*65536;
  const int tid = threadIdx.x;
  const int lr = tid >> 2, lc = tid & 3;
  const int w = tid >> 6, ln = tid & 63;
  const int lm = ln & 15, lk = (ln >> 4) * 8;

  floatx4 acc[4];
  #pragma unroll
  for (int tl=0;tl<4;tl++) acc[tl] = (floatx4){0.f,0.f,0.f,0.f};

  for (int k0 = 0; k0 < 256; k0 += 32){
    const short8 a_h = ldb8(mh + (size_t)(m0+lr)*256 + k0 + lc*8);
    const short8 a_l = ldb8(ml + (size_t)(m0+lr)*256 + k0 + lc*8);
    const short8 b_h = ldb8(Wh + (size_t)(n0+lr)*256 + k0 + lc*8);
    const short8 b_l = ldb8(Wl + (size_t)(n0+lr)*256 + k0 + lc*8);
    __syncthreads();
    *(short8*)&Ah[lr][lc*8] = a_h;
    *(short8*)&Al[lr][lc*8] = a_l;
    *(short8*)&Bh[lr][lc*8] = b_h;
    *(short8*)&Bl[lr][lc*8] = b_l;
    __syncthreads();
    const short8 ah8 = *(const short8*)&Ah[w*16+lm][lk];
    const short8 al8 = *(const short8*)&Al[w*16+lm][lk];
    #pragma unroll
    for (int tl = 0; tl < 4; tl++){
      const short8 bh8 = *(const short8*)&Bh[tl*16+lm][lk];
      const short8 bl8 = *(const short8*)&Bl[tl*16+lm][lk];
      acc[tl] = MFMA16(ah8, bh8, acc[tl]);
      acc[tl] = MFMA16(al8, bh8, acc[tl]);
      acc[tl] = MFMA16(ah8, bl8, acc[tl]);
      acc[tl] = MFMA16(al8, bl8, acc[tl]);
    }
  }

  #pragma unroll
  for (int tl = 0; tl < 4; tl++){
    const int f = n0 + tl*16 + lm;
    const float bf = bo[f];
    #pragma unroll
    for (int i=0;i<4;i++){
      const int m = m0 + w*16 + (ln >> 4)*4 + i;
      out[(size_t)m*256 + f] = acc[tl][i] + bf;
    }
  }
}

// ---------- launch ----------
extern "C" void kernel_launch(void* const* d_in, const int* in_sizes, int n_in,
                              void* d_out, int out_size, void* d_ws, size_t ws_size,
                              hipStream_t stream) {
  const float* x   = (const float*)d_in[0];
  const float* Wq  = (const float*)d_in[1];  const float* bq  = (const float*)d_in[2];
  const float* Wk  = (const float*)d_in[3];  const float* bk  = (const float*)d_in[4];
  const float* Wv  = (const float*)d_in[5];  const float* bv  = (const float*)d_in[6];
  const float* Wd  = (const float*)d_in[7];  const float* bd  = (const float*)d_in[8];
  const float* Wg  = (const float*)d_in[9];  const float* bg  = (const float*)d_in[10];
  const float* Wgp = (const float*)d_in[11]; const float* bgp = (const float*)d_in[12];
  const float* Wo  = (const float*)d_in[13]; const float* bo  = (const float*)d_in[14];

  char* base = (char*)d_ws;
  __hip_bfloat16* mixh = (__hip_bfloat16*)(base);                   // 4 MB
  __hip_bfloat16* mixl = (__hip_bfloat16*)(base + (size_t)( 4<<20));// 4 MB
  __hip_bfloat16* qh = (__hip_bfloat16*)(base + (size_t)( 8<<20));  // 4 MB
  __hip_bfloat16* ql = (__hip_bfloat16*)(base + (size_t)(12<<20));  // 4 MB
  __hip_bfloat16* kh = (__hip_bfloat16*)(base + (size_t)(16<<20));  // 4 MB
  __hip_bfloat16* kl = (__hip_bfloat16*)(base + (size_t)(20<<20));  // 4 MB
  _Float16* vth = (_Float16*)(base + (size_t)(24<<20));             // 4 MB (V^T hi)
  _Float16* vtl = (_Float16*)(base + (size_t)(28<<20));             // 4 MB (V^T lo)
  __hip_bfloat16* xh = (__hip_bfloat16*)(base + (size_t)(32<<20));  // 4 MB
  __hip_bfloat16* xl = (__hip_bfloat16*)(base + (size_t)(36<<20));  // 4 MB
  __hip_bfloat16* wh = (__hip_bfloat16*)(base + (size_t)(40<<20));        // 512 KB
  __hip_bfloat16* wl = (__hip_bfloat16*)(base + (size_t)(40<<20) + (512<<10)); // 512 KB
  float* xpart  = (float*)(base + (size_t)(41<<20));    // 512 KB
  float* gate_ws= (float*)(base + (size_t)(41<<20) + (512<<10));

  xpart_kernel<<<dim3(128,4), 256, 0, stream>>>(x, xpart, xh, xl);
  wconv_kernel<<<256, 256, 0, stream>>>(Wq, Wk, Wv, Wo, wh, wl);
  gate_kernel<<<4, 256, 0, stream>>>(xpart, Wg, bg, Wgp, bgp, gate_ws);
  qkv_gemm<<<dim3(128,12), 256, 0, stream>>>(xh, xl, wh, wl, bq, bk, bv,
                                             qh, ql, kh, kl, vth, vtl);
  attn_kernel<<<dim3(128,16), 512, 0, stream>>>(qh, ql, kh, kl, vth, vtl,
                                                Wd, bd, gate_ws, mixh, mixl);
  out_gemm<<<dim3(128,4), 256, 0, stream>>>(mixh, mixl, wh, wl, bo, (float*)d_out);
}